// Round 4
// baseline (2324.663 us; speedup 1.0000x reference)
//
#include <hip/hip_runtime.h>
#include <hip/hip_bf16.h>
#include <cmath>

#define DEV __device__ __forceinline__

constexpr int Bn = 16, Cn = 256, Nn = 4096;
constexpr int NHn = 8, CRn = 128, HALFn = 512;

typedef __hip_bfloat16 bf16;

DEV float b2f(bf16 v) { return __bfloat162float(v); }
DEV bf16 f2b(float v) { return __float2bfloat16(v); }
DEV float gelu_f(float x) { return 0.5f * x * (1.0f + erff(x * 0.70710678118654752f)); }

template <int NT>
DEV float2 block_sum2(float a, float b) {
    __shared__ float sh[2 * NT / 64];
    __syncthreads();  // protect reuse across calls
    int lane = threadIdx.x & 63, wv = threadIdx.x >> 6;
#pragma unroll
    for (int off = 32; off; off >>= 1) { a += __shfl_down(a, off); b += __shfl_down(b, off); }
    if (lane == 0) { sh[wv * 2] = a; sh[wv * 2 + 1] = b; }
    __syncthreads();
    float ta = 0.f, tb = 0.f;
#pragma unroll
    for (int i = 0; i < NT / 64; i++) { ta += sh[i * 2]; tb += sh[i * 2 + 1]; }
    return make_float2(ta, tb);
}

// ---- K1a: row/col means of each 64x64 channel map ----
__global__ void k_pool(const float* __restrict__ x, float* __restrict__ xmH, float* __restrict__ xmW) {
    __shared__ float t[4096];
    int blk = blockIdx.x;  // b*C + c
    const float* xp = x + (size_t)blk * 4096;
    int tid = threadIdx.x;
    for (int k = 0; k < 16; k++) t[tid + k * 256] = xp[tid + k * 256];
    __syncthreads();
    if (tid < 64) {
        float rs = 0.f, cs = 0.f;
        for (int w = 0; w < 64; w++) {
            int ws = (w + tid) & 63;  // skew to dodge bank conflicts on row sums
            rs += t[tid * 64 + ws];
            cs += t[w * 64 + tid];
        }
        xmH[(size_t)blk * 64 + tid] = rs * (1.f / 64.f);
        xmW[(size_t)blk * 64 + tid] = cs * (1.f / 64.f);
    }
}

// ---- K1b: depthwise conv1d(k=7,p=3) + GroupNorm(16 groups) + ReLU, both paths ----
__global__ void k_sda(const float* __restrict__ xmH, const float* __restrict__ xmW,
                      const float* __restrict__ w7, const float* __restrict__ gnw,
                      const float* __restrict__ gnb, float* __restrict__ xh, float* __restrict__ xw) {
    int b = blockIdx.x >> 4, grp = blockIdx.x & 15;
    int c0 = grp * 16;
    int tid = threadIdx.x;
    __shared__ float y[2][1024];
    for (int p = 0; p < 2; p++) {
        const float* xm = (p == 0 ? xmH : xmW) + ((size_t)b * Cn + c0) * 64;
        for (int e = tid; e < 1024; e += 256) {
            int ci = e >> 6, i = e & 63;
            float acc = 0.f;
            const float* wc = w7 + (c0 + ci) * 7;
#pragma unroll
            for (int j = 0; j < 7; j++) {
                int ii = i + j - 3;
                if (ii >= 0 && ii < 64) acc += xm[ci * 64 + ii] * wc[j];
            }
            y[p][e] = acc;
        }
    }
    __syncthreads();
    for (int p = 0; p < 2; p++) {
        float s = 0.f, s2 = 0.f;
        for (int e = tid; e < 1024; e += 256) { float v = y[p][e]; s += v; s2 += v * v; }
        float2 r = block_sum2<256>(s, s2);
        float m = r.x * (1.f / 1024.f);
        float var = r.y * (1.f / 1024.f) - m * m;
        float inv = rsqrtf(fmaxf(var, 0.f) + 1e-5f);
        float* outp = (p == 0 ? xh : xw) + ((size_t)b * Cn + c0) * 64;
        for (int e = tid; e < 1024; e += 256) {
            int ci = e >> 6, i = e & 63;
            float v = (y[p][e] - m) * inv * gnw[c0 + ci] + gnb[c0 + ci];
            outp[ci * 64 + i] = v > 0.f ? v : 0.f;
        }
    }
}

// ---- K2: gating, tokenization, LayerNorm1 (one token per block) ----
// t0 (residual) is NOT stored: k_proj / k_fc2 recompute it in fp32 from x,xh,xw.
__global__ void k_gate_norm1(const float* __restrict__ x, const float* __restrict__ xh,
                             const float* __restrict__ xw, const float* __restrict__ n1w,
                             const float* __restrict__ n1b, bf16* __restrict__ tn) {
    int blk = blockIdx.x;  // b*N + n
    int b = blk >> 12, n = blk & 4095;
    int hh = n >> 6, ww = n & 63;
    int c = threadIdx.x;
    float v = x[(((size_t)b * Cn + c) * 64 + hh) * 64 + ww] *
              xh[((size_t)b * Cn + c) * 64 + hh] * xw[((size_t)b * Cn + c) * 64 + ww];
    float2 r = block_sum2<256>(v, v * v);
    float m = r.x * (1.f / 256.f), var = r.y * (1.f / 256.f) - m * m;
    float inv = rsqrtf(fmaxf(var, 0.f) + 1e-6f);
    tn[(size_t)blk * 256 + c] = f2b((v - m) * inv * n1w[c] + n1b[c]);
}

// ---- K4: depthwise 4x4 stride-4 reduction #1: 64x64 -> 16x16 ----
__global__ void k_red1(const bf16* __restrict__ tn, const float* __restrict__ rw,
                       const float* __restrict__ rb, float* __restrict__ red1) {
    int blk = blockIdx.x;  // b*C + c
    int b = blk >> 8, c = blk & 255;
    int t = threadIdx.x;  // yo*16 + xo
    int yo = t >> 4, xo = t & 15;
    float acc = rb[c];
    const float* w = rw + c * 16;
    const bf16* base = tn + (size_t)b * Nn * Cn + c;
#pragma unroll
    for (int dy = 0; dy < 4; dy++)
#pragma unroll
        for (int dx = 0; dx < 4; dx++)
            acc += b2f(base[(size_t)((yo * 4 + dy) * 64 + xo * 4 + dx) * Cn]) * w[dy * 4 + dx];
    red1[(size_t)blk * 256 + t] = acc;
}

// ---- K5: reduction #2: 16x16 -> 4x4 ----
__global__ void k_red2(const float* __restrict__ red1, const float* __restrict__ rw,
                       const float* __restrict__ rb, float* __restrict__ red2) {
    int idx = blockIdx.x * 256 + threadIdx.x;  // (b*C+c)*16 + t
    int t = idx & 15, bc = idx >> 4;
    int c = bc & 255;
    int yo = t >> 2, xo = t & 3;
    float acc = rb[c];
    const float* w = rw + c * 16;
    const float* base = red1 + (size_t)bc * 256;
#pragma unroll
    for (int dy = 0; dy < 4; dy++)
#pragma unroll
        for (int dx = 0; dx < 4; dx++)
            acc += base[(yo * 4 + dy) * 16 + xo * 4 + dx] * w[dy * 4 + dx];
    red2[idx] = acc;
}

// ---- K6: depthwise 3x3 pad1 on 4x4 map ----
__global__ void k_dw3(const float* __restrict__ in, const float* __restrict__ w9,
                      const float* __restrict__ bb, float* __restrict__ outp) {
    int idx = blockIdx.x * 256 + threadIdx.x;
    int t = idx & 15, bc = idx >> 4, c = bc & 255;
    int y = t >> 2, x = t & 3;
    float acc = bb[c];
    const float* w = w9 + c * 9;
    const float* base = in + (size_t)bc * 16;
#pragma unroll
    for (int dy = -1; dy <= 1; dy++)
#pragma unroll
        for (int dx = -1; dx <= 1; dx++) {
            int yy = y + dy, xx = x + dx;
            if (yy >= 0 && yy < 4 && xx >= 0 && xx < 4)
                acc += base[yy * 4 + xx] * w[(dy + 1) * 3 + (dx + 1)];
        }
    outp[idx] = acc;
}

// ---- K7: 1x1 conv (C->CR) + LayerNorm(eps 1e-5) + GELU -> _x tokens [B,16,128] ----
__global__ void k_conv1x1_ln(const float* __restrict__ dwr, const float* __restrict__ cw,
                             const float* __restrict__ cb, const float* __restrict__ naw,
                             const float* __restrict__ nab, float* __restrict__ xr) {
    int b = blockIdx.x >> 4, m = blockIdx.x & 15;
    int tid = threadIdx.x;  // 128 threads
    __shared__ float in[256];
    for (int c = tid; c < 256; c += 128) in[c] = dwr[((size_t)b * Cn + c) * 16 + m];
    __syncthreads();
    float acc = cb[tid];
    const float* w = cw + tid * 256;
    for (int c = 0; c < 256; c++) acc += in[c] * w[c];
    float2 r = block_sum2<128>(acc, acc * acc);
    float mm = r.x * (1.f / 128.f), var = r.y * (1.f / 128.f) - mm * mm;
    float inv = rsqrtf(fmaxf(var, 0.f) + 1e-5f);
    float z = (acc - mm) * inv * naw[tid] + nab[tid];
    xr[(size_t)blockIdx.x * 128 + tid] = gelu_f(z);
}

// ---- K8a: K and V projections of _x ----
__global__ void k_kv(const float* __restrict__ xr, const float* __restrict__ kw,
                     const float* __restrict__ vw, float* __restrict__ kbuf, float* __restrict__ v0) {
    int bm = blockIdx.x;
    int tid = threadIdx.x;
    __shared__ float in[128];
    if (tid < 128) in[tid] = xr[(size_t)bm * 128 + tid];
    __syncthreads();
    float acc = 0.f;
    for (int i = 0; i < 128; i++) acc += in[i] * vw[i * 256 + tid];
    v0[(size_t)bm * 256 + tid] = acc;
    if (tid < 128) {
        float ak = 0.f;
        for (int i = 0; i < 128; i++) ak += in[i] * kw[i * 128 + tid];
        kbuf[(size_t)bm * 128 + tid] = ak;
    }
}

// ---- K8b: CPE depthwise 3x3 on 4x4 V map, added to V ----
__global__ void k_cpe(const float* __restrict__ v0, const float* __restrict__ cw,
                      const float* __restrict__ cb, float* __restrict__ v) {
    int idx = blockIdx.x * 256 + threadIdx.x;  // (b*16+m)*256 + c
    int c = idx & 255, bm = idx >> 8;
    int b = bm >> 4, m = bm & 15;
    int y = m >> 2, x = m & 3;
    float acc = v0[idx] + cb[c];
#pragma unroll
    for (int dy = -1; dy <= 1; dy++)
#pragma unroll
        for (int dx = -1; dx <= 1; dx++) {
            int yy = y + dy, xx = x + dx;
            if (yy >= 0 && yy < 4 && xx >= 0 && xx < 4)
                acc += v0[((size_t)b * 16 + yy * 4 + xx) * 256 + c] * cw[c * 9 + (dy + 1) * 3 + (dx + 1)];
        }
    v[idx] = acc;
}

// ---- K9: Q projection, 8 rows per block register-blocked ----
__global__ void k_q(const bf16* __restrict__ tn, const float* __restrict__ qw, bf16* __restrict__ q) {
    int blk = blockIdx.x;
    int tid = threadIdx.x;
    int j = tid & 127, half = tid >> 7;
    __shared__ float in[8][256];
    size_t row0 = (size_t)blk * 8;
    for (int i = tid; i < 8 * 256; i += 256) in[i >> 8][i & 255] = b2f(tn[row0 * 256 + i]);
    __syncthreads();
    float acc[4] = {0.f, 0.f, 0.f, 0.f};
    for (int c = 0; c < 256; c++) {
        float w = qw[c * 128 + j];
#pragma unroll
        for (int r = 0; r < 4; r++) acc[r] += in[half * 4 + r][c] * w;
    }
#pragma unroll
    for (int r = 0; r < 4; r++) q[(row0 + half * 4 + r) * 128 + j] = f2b(acc[r]);
}

// ---- K10: fused attention (scores + softmax + PV) per (b,h), Nr=16 in LDS ----
__global__ void k_attn(const bf16* __restrict__ q, const float* __restrict__ kbuf,
                       const float* __restrict__ v, bf16* o) {
    int blk = blockIdx.x;
    int chunk = blk & 7, bh = blk >> 3;
    int h = bh & 7, b = bh >> 3;
    __shared__ float ks[16][16];
    __shared__ float vs[16][32];
    int tid = threadIdx.x;
    {
        int m = tid >> 4, d = tid & 15;
        ks[m][d] = kbuf[((size_t)(b * 16 + m)) * 128 + h * 16 + d];
    }
    for (int i = tid; i < 512; i += 256) {
        int m = i >> 5, e = i & 31;
        vs[m][e] = v[((size_t)(b * 16 + m)) * 256 + h * 32 + e];
    }
    __syncthreads();
    for (int it = 0; it < 2; it++) {
        int n = chunk * 512 + it * 256 + tid;
        const bf16* qp = q + ((size_t)b * Nn + n) * 128 + h * 16;
        float qr[16];
#pragma unroll
        for (int d = 0; d < 16; d++) qr[d] = b2f(qp[d]);
        float sc[16];
        float mx = -1e30f;
#pragma unroll
        for (int m = 0; m < 16; m++) {
            float s = 0.f;
#pragma unroll
            for (int d = 0; d < 16; d++) s += qr[d] * ks[m][d];
            s *= 0.25f;
            sc[m] = s;
            mx = fmaxf(mx, s);
        }
        float den = 0.f;
#pragma unroll
        for (int m = 0; m < 16; m++) { sc[m] = expf(sc[m] - mx); den += sc[m]; }
        float rden = 1.f / den;
        float ov[32];
#pragma unroll
        for (int e = 0; e < 32; e++) ov[e] = 0.f;
#pragma unroll
        for (int m = 0; m < 16; m++) {
            float p = sc[m] * rden;
#pragma unroll
            for (int e = 0; e < 32; e++) ov[e] += p * vs[m][e];
        }
        bf16* op = o + ((size_t)b * Nn + n) * 256 + h * 32;
#pragma unroll
        for (int e = 0; e < 32; e++) op[e] = f2b(ov[e]);
    }
}

// ---- K11: proj + bias; residual t0 recomputed fp32; store proj_out bf16 + LayerNorm2 ----
__global__ void k_proj(const bf16* o, const float* __restrict__ pw,
                       const float* __restrict__ pb, const float* __restrict__ n2w,
                       const float* __restrict__ n2b, const float* __restrict__ x,
                       const float* __restrict__ xh, const float* __restrict__ xw,
                       bf16* __restrict__ po, bf16* tn2) {
    __shared__ float in[16][256];
    __shared__ float t1s[16][256];
    int blk = blockIdx.x, tid = threadIdx.x;
    size_t row0 = (size_t)blk * 16;
    for (int i = tid; i < 16 * 256; i += 256) in[i >> 8][i & 255] = b2f(o[row0 * 256 + i]);
    __syncthreads();
    float acc[16];
#pragma unroll
    for (int r = 0; r < 16; r++) acc[r] = 0.f;
    int c = tid;
    for (int k2 = 0; k2 < 256; k2++) {
        float w = pw[k2 * 256 + c];
#pragma unroll
        for (int r = 0; r < 16; r++) acc[r] += in[r][k2] * w;
    }
    float bias = pb[c];
    // recompute residual t0 = x * xh * xw in fp32 (block spans one hh row: n0%64 in {0,16,32,48})
    int b = (int)(row0 >> 12);
    int n0 = (int)(row0 & 4095);
    int hh = n0 >> 6, w0 = n0 & 63;
    float hgate = xh[((size_t)b * Cn + c) * 64 + hh];
    const float* xrow = x + (((size_t)b * Cn + c) * 64 + hh) * 64 + w0;
    const float* wrow = xw + ((size_t)b * Cn + c) * 64 + w0;
    for (int r = 0; r < 16; r++) {
        float pv = acc[r] + bias;
        float t1v = pv + xrow[r] * hgate * wrow[r];
        t1s[r][c] = t1v;
        po[(row0 + r) * 256 + c] = f2b(pv);
    }
    __syncthreads();
    int wv = tid >> 6, lane = tid & 63;
    float nw[4], nb[4];
#pragma unroll
    for (int k2 = 0; k2 < 4; k2++) { nw[k2] = n2w[lane + k2 * 64]; nb[k2] = n2b[lane + k2 * 64]; }
    for (int rr = 0; rr < 4; rr++) {
        int r = wv * 4 + rr;
        float s = 0.f, s2 = 0.f;
#pragma unroll
        for (int k2 = 0; k2 < 4; k2++) { float v = t1s[r][lane + k2 * 64]; s += v; s2 += v * v; }
#pragma unroll
        for (int off2 = 32; off2; off2 >>= 1) { s += __shfl_down(s, off2); s2 += __shfl_down(s2, off2); }
        s = __shfl(s, 0); s2 = __shfl(s2, 0);
        float m = s * (1.f / 256.f), var = s2 * (1.f / 256.f) - m * m;
        float inv = rsqrtf(fmaxf(var, 0.f) + 1e-6f);
#pragma unroll
        for (int k2 = 0; k2 < 4; k2++) {
            int cc = lane + k2 * 64;
            float v = t1s[r][cc];
            tn2[(row0 + r) * 256 + cc] = f2b((v - m) * inv * nw[k2] + nb[k2]);
        }
    }
}

// ---- K12: fc1 + bias + gelu, split; x2 half gets LayerNorm(gnorm); bf16 outputs ----
__global__ void k_fc1(const bf16* __restrict__ tn2, const float* __restrict__ fw,
                      const float* __restrict__ fb, const float* __restrict__ gnw,
                      const float* __restrict__ gnb, bf16* __restrict__ x1,
                      bf16* __restrict__ x2n) {
    __shared__ float in[16][256];
    __shared__ float x2s[16][512];
    int blk = blockIdx.x, tid = threadIdx.x;
    size_t row0 = (size_t)blk * 16;
    for (int i = tid; i < 16 * 256; i += 256) in[i >> 8][i & 255] = b2f(tn2[row0 * 256 + i]);
    __syncthreads();
    for (int p = 0; p < 4; p++) {
        int j = p * 256 + tid;
        float acc[16];
#pragma unroll
        for (int r = 0; r < 16; r++) acc[r] = 0.f;
        for (int c = 0; c < 256; c++) {
            float w = fw[c * 1024 + j];
#pragma unroll
            for (int r = 0; r < 16; r++) acc[r] += in[r][c] * w;
        }
        float bias = fb[j];
        if (p < 2) {
            for (int r = 0; r < 16; r++) {
                float g = gelu_f(acc[r] + bias);
                x1[(row0 + r) * 512 + j] = f2b(g);
            }
        } else {
            int j2 = j - 512;
            for (int r = 0; r < 16; r++) x2s[r][j2] = gelu_f(acc[r] + bias);
        }
    }
    __syncthreads();
    int wv = tid >> 6, lane = tid & 63;
    float nw[8], nb[8];
#pragma unroll
    for (int k2 = 0; k2 < 8; k2++) { nw[k2] = gnw[lane + k2 * 64]; nb[k2] = gnb[lane + k2 * 64]; }
    for (int rr = 0; rr < 4; rr++) {
        int r = wv * 4 + rr;
        float s = 0.f, s2 = 0.f;
#pragma unroll
        for (int k2 = 0; k2 < 8; k2++) { float v = x2s[r][lane + k2 * 64]; s += v; s2 += v * v; }
#pragma unroll
        for (int off2 = 32; off2; off2 >>= 1) { s += __shfl_down(s, off2); s2 += __shfl_down(s2, off2); }
        s = __shfl(s, 0); s2 = __shfl(s2, 0);
        float m = s * (1.f / 512.f), var = s2 * (1.f / 512.f) - m * m;
        float inv = rsqrtf(fmaxf(var, 0.f) + 1e-5f);
#pragma unroll
        for (int k2 = 0; k2 < 8; k2++) {
            int e = lane + k2 * 64;
            float v = (x2s[r][e] - m) * inv * nw[k2] + nb[k2];
            x2n[(row0 + r) * 512 + e] = f2b(v);
        }
    }
}

// ---- K13: gate = x1 * dwconv3x3(x2n), in-place into x1 buffer ----
__global__ void k_gatec(const bf16* __restrict__ x2n, const float* __restrict__ gw,
                        const float* __restrict__ gb, bf16* __restrict__ x1io) {
    size_t idx = (size_t)blockIdx.x * 256 + threadIdx.x;  // (b*N+n)*512 + c
    int c = (int)(idx & 511);
    size_t bn = idx >> 9;
    int n = (int)(bn & 4095);
    size_t b = bn >> 12;
    int y = n >> 6, x = n & 63;
    float acc = gb[c];
    const float* w = gw + c * 9;
#pragma unroll
    for (int dy = -1; dy <= 1; dy++)
#pragma unroll
        for (int dx = -1; dx <= 1; dx++) {
            int yy = y + dy, xx = x + dx;
            if (yy >= 0 && yy < 64 && xx >= 0 && xx < 64)
                acc += b2f(x2n[(b * Nn + yy * 64 + xx) * 512 + c]) * w[(dy + 1) * 3 + (dx + 1)];
        }
    float g = b2f(x1io[idx]) * acc;
    x1io[idx] = f2b(g);
}

// ---- K14: fc2 + bias + residual(recomputed fp32 + proj_out), write NCHW fp32 output ----
__global__ void k_fc2(const bf16* __restrict__ g, const float* __restrict__ fw,
                      const float* __restrict__ fb, const bf16* __restrict__ po,
                      const float* __restrict__ x, const float* __restrict__ xh,
                      const float* __restrict__ xw, float* outp) {
    __shared__ float in[16][512];
    int blk = blockIdx.x, tid = threadIdx.x;
    size_t row0 = (size_t)blk * 16;
    for (int i = tid; i < 16 * 512; i += 256) in[i >> 9][i & 511] = b2f(g[row0 * 512 + i]);
    __syncthreads();
    int c = tid;
    float acc[16];
#pragma unroll
    for (int r = 0; r < 16; r++) acc[r] = 0.f;
    for (int k2 = 0; k2 < 512; k2++) {
        float w = fw[k2 * 256 + c];
#pragma unroll
        for (int r = 0; r < 16; r++) acc[r] += in[r][k2] * w;
    }
    float bias = fb[c];
    int b = (int)(row0 >> 12);
    int n0 = (int)(row0 & 4095);
    int hh = n0 >> 6, w0 = n0 & 63;
    float hgate = xh[((size_t)b * Cn + c) * 64 + hh];
    const float* xrow = x + (((size_t)b * Cn + c) * 64 + hh) * 64 + w0;
    const float* wrow = xw + ((size_t)b * Cn + c) * 64 + w0;
    for (int r = 0; r < 16; r++) {
        float t1v = b2f(po[(row0 + r) * 256 + c]) + xrow[r] * hgate * wrow[r];
        float v = acc[r] + bias + t1v;
        outp[((size_t)b * 256 + c) * 4096 + n0 + r] = v;
    }
}

extern "C" void kernel_launch(void* const* d_in, const int* in_sizes, int n_in,
                              void* d_out, int out_size, void* d_ws, size_t ws_size,
                              hipStream_t stream) {
    const float* x = (const float*)d_in[0];
    const float* sda_conv_w = (const float*)d_in[1];
    const float* sda_gn_w = (const float*)d_in[2];
    const float* sda_gn_b = (const float*)d_in[3];
    const float* norm1_w = (const float*)d_in[4];
    const float* norm1_b = (const float*)d_in[5];
    const float* red_w = (const float*)d_in[6];
    const float* red_b = (const float*)d_in[7];
    const float* dw_w = (const float*)d_in[8];
    const float* dw_b = (const float*)d_in[9];
    const float* conv_w = (const float*)d_in[10];
    const float* conv_b = (const float*)d_in[11];
    const float* na_w = (const float*)d_in[12];
    const float* na_b = (const float*)d_in[13];
    const float* q_w = (const float*)d_in[14];
    const float* k_w = (const float*)d_in[15];
    const float* v_w = (const float*)d_in[16];
    const float* cpe_w = (const float*)d_in[17];
    const float* cpe_b = (const float*)d_in[18];
    const float* proj_w = (const float*)d_in[19];
    const float* proj_b = (const float*)d_in[20];
    const float* norm2_w = (const float*)d_in[21];
    const float* norm2_b = (const float*)d_in[22];
    const float* fc1_w = (const float*)d_in[23];
    const float* fc1_b = (const float*)d_in[24];
    const float* gnorm_w = (const float*)d_in[25];
    const float* gnorm_b = (const float*)d_in[26];
    const float* gconv_w = (const float*)d_in[27];
    const float* gconv_b = (const float*)d_in[28];
    const float* fc2_w = (const float*)d_in[29];
    const float* fc2_b = (const float*)d_in[30];
    float* outp = (float*)d_out;

    char* ws = (char*)d_ws;
    size_t off = 0;
    auto alloc = [&](size_t bytes) -> char* {
        char* p = ws + off;
        off += (bytes + 255) & ~(size_t)255;
        return p;
    };
    // ws total ~105 MB (proven safe in round 3). d_out (67 MB fp32) doubles as
    // bf16 scratch for tn -> o -> tn2 (33.5 MB), all dead before k_fc2's final write.
    bf16* po = (bf16*)alloc((size_t)Bn * Nn * Cn * 2);        // proj+bias (no residual), 33.5 MB
    char* arena2 = alloc((size_t)Bn * Nn * HALFn * 2);        // qb then x1 (33.5 MB)
    char* arena3 = alloc((size_t)Bn * Nn * HALFn * 2);        // red1 then x2n (33.5 MB)
    float* xmH = (float*)alloc((size_t)Bn * Cn * 64 * 4);
    float* xmW = (float*)alloc((size_t)Bn * Cn * 64 * 4);
    float* xh = (float*)alloc((size_t)Bn * Cn * 64 * 4);
    float* xw = (float*)alloc((size_t)Bn * Cn * 64 * 4);
    float* red2 = (float*)alloc((size_t)Bn * Cn * 16 * 4);
    float* dwr = (float*)alloc((size_t)Bn * Cn * 16 * 4);
    float* xr = (float*)alloc((size_t)Bn * 16 * 128 * 4);
    float* kb = (float*)alloc((size_t)Bn * 16 * 128 * 4);
    float* v0 = (float*)alloc((size_t)Bn * 16 * 256 * 4);
    float* vb = (float*)alloc((size_t)Bn * 16 * 256 * 4);

    bf16* tn = (bf16*)d_out;       // norm1 out -> o -> tn2, dies before final write
    bf16* qb = (bf16*)arena2;      // dies after k_attn
    bf16* x1 = (bf16*)arena2;      // born at k_fc1
    float* red1 = (float*)arena3;  // dies after k_red2
    bf16* x2n = (bf16*)arena3;     // born at k_fc1

    k_pool<<<Bn * Cn, 256, 0, stream>>>(x, xmH, xmW);
    k_sda<<<Bn * 16, 256, 0, stream>>>(xmH, xmW, sda_conv_w, sda_gn_w, sda_gn_b, xh, xw);
    k_gate_norm1<<<Bn * Nn, 256, 0, stream>>>(x, xh, xw, norm1_w, norm1_b, tn);
    k_red1<<<Bn * Cn, 256, 0, stream>>>(tn, red_w, red_b, red1);
    k_red2<<<256, 256, 0, stream>>>(red1, red_w, red_b, red2);
    k_dw3<<<256, 256, 0, stream>>>(red2, dw_w, dw_b, dwr);
    k_conv1x1_ln<<<Bn * 16, 128, 0, stream>>>(dwr, conv_w, conv_b, na_w, na_b, xr);
    k_kv<<<Bn * 16, 256, 0, stream>>>(xr, k_w, v_w, kb, v0);
    k_cpe<<<256, 256, 0, stream>>>(v0, cpe_w, cpe_b, vb);
    k_q<<<Bn * Nn / 8, 256, 0, stream>>>(tn, q_w, qb);
    k_attn<<<Bn * NHn * 8, 256, 0, stream>>>(qb, kb, vb, tn);  // o overwrites tn region
    k_proj<<<Bn * Nn / 16, 256, 0, stream>>>(tn, proj_w, proj_b, norm2_w, norm2_b,
                                             x, xh, xw, po, tn);
    k_fc1<<<Bn * Nn / 16, 256, 0, stream>>>(tn, fc1_w, fc1_b, gnorm_w, gnorm_b, x1, x2n);
    k_gatec<<<(Bn * Nn * HALFn) / 256, 256, 0, stream>>>(x2n, gconv_w, gconv_b, x1);
    k_fc2<<<Bn * Nn / 16, 256, 0, stream>>>(x1, fc2_w, fc2_b, po, x, xh, xw, outp);
}

// Round 5
// 1360.301 us; speedup vs baseline: 1.7089x; 1.7089x over previous
//
#include <hip/hip_runtime.h>
#include <hip/hip_bf16.h>
#include <cmath>

#define DEV __device__ __forceinline__

constexpr int Bn = 16, Cn = 256, Nn = 4096;
constexpr int NHn = 8, CRn = 128, HALFn = 512;
constexpr int Mtot = Bn * Nn;  // 65536 token rows

typedef __hip_bfloat16 bf16;
typedef __attribute__((ext_vector_type(8))) short bf16x8;
typedef __attribute__((ext_vector_type(4))) float f32x4;

DEV float b2f(bf16 v) { return __bfloat162float(v); }
DEV bf16 f2b(float v) { return __float2bfloat16(v); }
DEV float gelu_f(float x) { return 0.5f * x * (1.0f + erff(x * 0.70710678118654752f)); }

template <int NT>
DEV float2 block_sum2(float a, float b) {
    __shared__ float sh[2 * NT / 64];
    __syncthreads();
    int lane = threadIdx.x & 63, wv = threadIdx.x >> 6;
#pragma unroll
    for (int off = 32; off; off >>= 1) { a += __shfl_down(a, off); b += __shfl_down(b, off); }
    if (lane == 0) { sh[wv * 2] = a; sh[wv * 2 + 1] = b; }
    __syncthreads();
    float ta = 0.f, tb = 0.f;
#pragma unroll
    for (int i = 0; i < NT / 64; i++) { ta += sh[i * 2]; tb += sh[i * 2 + 1]; }
    return make_float2(ta, tb);
}

// ================= MFMA GEMM machinery =================
// Block: 256 threads = 4 waves. Tile: 64(M) x 64(N). K staged in 128-chunks.
// LDS rows padded to 136 shorts (272 B, 16B-aligned, 2-way-bank-free).
constexpr int LDP = 136;

DEV void stage64(const bf16* __restrict__ g, int stride, short* lds) {
    int t = threadIdx.x;
    int r = t >> 2, seg = t & 3;
    const uint4* src = (const uint4*)(g + (size_t)r * stride + seg * 32);
    uint4* dst = (uint4*)(lds + r * LDP + seg * 32);
#pragma unroll
    for (int i = 0; i < 4; i++) dst[i] = src[i];
}

DEV void compute_chunk(const short* lA, const short* lW, f32x4* acc) {
    int lane = threadIdx.x & 63;
    int w = threadIdx.x >> 6;
    const short* pa = lA + (w * 16 + (lane & 15)) * LDP + (lane >> 4) * 8;
    const short* pb = lW + (lane & 15) * LDP + (lane >> 4) * 8;
#pragma unroll
    for (int kt = 0; kt < 4; kt++) {  // 4 k-tiles of 32 per 128-chunk
        bf16x8 a = *(const bf16x8*)(pa + kt * 32);
#pragma unroll
        for (int nt = 0; nt < 4; nt++) {
            bf16x8 b = *(const bf16x8*)(pb + nt * 16 * LDP + kt * 32);
            acc[nt] = __builtin_amdgcn_mfma_f32_16x16x32_bf16(a, b, acc[nt], 0, 0, 0);
        }
    }
}

template <int K>
DEV void gemm_main(const bf16* __restrict__ A, const bf16* __restrict__ Wt,
                   int mblk, int nblk, short* lA, short* lW, f32x4* acc) {
#pragma unroll
    for (int nt = 0; nt < 4; nt++)
#pragma unroll
        for (int i = 0; i < 4; i++) acc[nt][i] = 0.f;
    for (int kc = 0; kc < K / 128; kc++) {
        if (kc) __syncthreads();
        stage64(A + (size_t)mblk * 64 * K + kc * 128, K, lA);
        stage64(Wt + (size_t)nblk * 64 * K + kc * 128, K, lW);
        __syncthreads();
        compute_chunk(lA, lW, acc);
    }
}

// ---- weight convert fp32[K][N] -> bf16 transposed [N][K] ----
__global__ void k_cvtw(const float* __restrict__ W, bf16* __restrict__ Wt, int K, int N) {
    __shared__ float t[32][33];
    int ntn = N >> 5;
    int bx = blockIdx.x % ntn, by = blockIdx.x / ntn;
    int tx = threadIdx.x & 31, ty = threadIdx.x >> 5;
#pragma unroll
    for (int i = 0; i < 4; i++)
        t[ty + i * 8][tx] = W[(size_t)(by * 32 + ty + i * 8) * N + bx * 32 + tx];
    __syncthreads();
#pragma unroll
    for (int i = 0; i < 4; i++)
        Wt[(size_t)(bx * 32 + ty + i * 8) * K + by * 32 + tx] = f2b(t[tx][ty + i * 8]);
}

// ---- Q = tn @ q_w   (K=256, N=128, no bias) ----
__global__ void gemm_q(const bf16* __restrict__ A, const bf16* __restrict__ Wt,
                       bf16* __restrict__ out) {
    __shared__ short lA[64 * LDP], lW[64 * LDP];
    int mblk = blockIdx.x >> 1, nblk = blockIdx.x & 1;
    f32x4 acc[4];
    gemm_main<256>(A, Wt, mblk, nblk, lA, lW, acc);
    int lane = threadIdx.x & 63, w = threadIdx.x >> 6, m16 = lane & 15, quad = lane >> 4;
    size_t rowb = (size_t)mblk * 64 + w * 16 + quad * 4;
#pragma unroll
    for (int nt = 0; nt < 4; nt++) {
        int col = nblk * 64 + nt * 16 + m16;
#pragma unroll
        for (int reg = 0; reg < 4; reg++) out[(rowb + reg) * 128 + col] = f2b(acc[nt][reg]);
    }
}

// ---- po = o @ proj_w + proj_b   (K=256, N=256) ----
__global__ void gemm_proj(const bf16* __restrict__ A, const bf16* __restrict__ Wt,
                          const float* __restrict__ pb, bf16* __restrict__ out) {
    __shared__ short lA[64 * LDP], lW[64 * LDP];
    int mblk = blockIdx.x >> 2, nblk = blockIdx.x & 3;
    f32x4 acc[4];
    gemm_main<256>(A, Wt, mblk, nblk, lA, lW, acc);
    int lane = threadIdx.x & 63, w = threadIdx.x >> 6, m16 = lane & 15, quad = lane >> 4;
    size_t rowb = (size_t)mblk * 64 + w * 16 + quad * 4;
#pragma unroll
    for (int nt = 0; nt < 4; nt++) {
        int col = nblk * 64 + nt * 16 + m16;
        float bv = pb[col];
#pragma unroll
        for (int reg = 0; reg < 4; reg++) out[(rowb + reg) * 256 + col] = f2b(acc[nt][reg] + bv);
    }
}

// ---- h = gelu(tn2 @ fc1_w + fc1_b); cols<512 -> x1, cols>=512 -> x2b (pre-LN) ----
__global__ void gemm_fc1(const bf16* __restrict__ A, const bf16* __restrict__ Wt,
                         const float* __restrict__ fb, bf16* __restrict__ x1,
                         bf16* __restrict__ x2b) {
    __shared__ short lA[64 * LDP], lW[64 * LDP];
    int mblk = blockIdx.x >> 4, nblk = blockIdx.x & 15;
    f32x4 acc[4];
    gemm_main<256>(A, Wt, mblk, nblk, lA, lW, acc);
    int tid = threadIdx.x;
    int lane = tid & 63, w = tid >> 6, m16 = lane & 15, quad = lane >> 4;
    __syncthreads();  // all waves done reading lA before reuse
    bf16* ldsO = (bf16*)lA;  // 64 x 72 bf16 tile (9216 B < 17408 B)
    int rl0 = w * 16 + quad * 4;
#pragma unroll
    for (int nt = 0; nt < 4; nt++) {
        int col = nblk * 64 + nt * 16 + m16;
        float bv = fb[col];
#pragma unroll
        for (int reg = 0; reg < 4; reg++)
            ldsO[(rl0 + reg) * 72 + nt * 16 + m16] = f2b(gelu_f(acc[nt][reg] + bv));
    }
    __syncthreads();
    int lm = tid >> 2, seg = tid & 3;
    int colg = nblk * 64 + seg * 16;
    bf16* dst = (colg < 512) ? (x1 + (size_t)(mblk * 64 + lm) * 512 + colg)
                             : (x2b + (size_t)(mblk * 64 + lm) * 512 + colg - 512);
    const uint4* s = (const uint4*)(ldsO + lm * 72 + seg * 16);
    uint4* d = (uint4*)dst;
    d[0] = s[0];
    d[1] = s[1];
}

// ---- out = g @ fc2_w + fc2_b + po + x*xh*xw, NCHW fp32 via LDS transpose ----
__global__ void gemm_fc2(const bf16* __restrict__ A, const bf16* __restrict__ Wt,
                         const float* __restrict__ fb, const bf16* __restrict__ po,
                         const float* __restrict__ x, const float* __restrict__ xh,
                         const float* __restrict__ xw, float* __restrict__ outp) {
    __shared__ short lA[64 * LDP], lW[64 * LDP];
    int mblk = blockIdx.x >> 2, nblk = blockIdx.x & 3;
    f32x4 acc[4];
    gemm_main<512>(A, Wt, mblk, nblk, lA, lW, acc);
    int tid = threadIdx.x;
    int lane = tid & 63, w = tid >> 6, m16 = lane & 15, quad = lane >> 4;
    __syncthreads();
    float* ldsF = (float*)lA;  // 64 x 65 fp32 (16640 B < 17408 B)
    int b = mblk >> 6;
    int hh = mblk & 63;
    int n0 = hh * 64;
    int rl0 = w * 16 + quad * 4;
#pragma unroll
    for (int nt = 0; nt < 4; nt++) {
        int c = nblk * 64 + nt * 16 + m16;
        float bv = fb[c];
        float hg = xh[((size_t)b * 256 + c) * 64 + hh];
        const float* xp = x + (((size_t)b * 256 + c) * 64 + hh) * 64 + rl0;
        const float* wp = xw + ((size_t)b * 256 + c) * 64 + rl0;
        const bf16* pp = po + ((size_t)mblk * 64 + rl0) * 256 + c;
#pragma unroll
        for (int reg = 0; reg < 4; reg++) {
            float v = acc[nt][reg] + bv + b2f(pp[reg * 256]) + xp[reg] * hg * wp[reg];
            ldsF[(rl0 + reg) * 65 + nt * 16 + m16] = v;
        }
    }
    __syncthreads();
    int cl = tid >> 2, ms = tid & 3;
    size_t ob = ((size_t)b * 256 + nblk * 64 + cl) * 4096 + n0 + ms * 16;
#pragma unroll
    for (int g2 = 0; g2 < 4; g2++) {
        float4 v4 = make_float4(ldsF[(ms * 16 + g2 * 4 + 0) * 65 + cl],
                                ldsF[(ms * 16 + g2 * 4 + 1) * 65 + cl],
                                ldsF[(ms * 16 + g2 * 4 + 2) * 65 + cl],
                                ldsF[(ms * 16 + g2 * 4 + 3) * 65 + cl]);
        *(float4*)(outp + ob + g2 * 4) = v4;
    }
}

// ================= non-GEMM kernels (from passing round 4) =================

__global__ void k_pool(const float* __restrict__ x, float* __restrict__ xmH, float* __restrict__ xmW) {
    __shared__ float t[4096];
    int blk = blockIdx.x;
    const float* xp = x + (size_t)blk * 4096;
    int tid = threadIdx.x;
    for (int k = 0; k < 16; k++) t[tid + k * 256] = xp[tid + k * 256];
    __syncthreads();
    if (tid < 64) {
        float rs = 0.f, cs = 0.f;
        for (int w = 0; w < 64; w++) {
            int ws = (w + tid) & 63;
            rs += t[tid * 64 + ws];
            cs += t[w * 64 + tid];
        }
        xmH[(size_t)blk * 64 + tid] = rs * (1.f / 64.f);
        xmW[(size_t)blk * 64 + tid] = cs * (1.f / 64.f);
    }
}

__global__ void k_sda(const float* __restrict__ xmH, const float* __restrict__ xmW,
                      const float* __restrict__ w7, const float* __restrict__ gnw,
                      const float* __restrict__ gnb, float* __restrict__ xh, float* __restrict__ xw) {
    int b = blockIdx.x >> 4, grp = blockIdx.x & 15;
    int c0 = grp * 16;
    int tid = threadIdx.x;
    __shared__ float y[2][1024];
    for (int p = 0; p < 2; p++) {
        const float* xm = (p == 0 ? xmH : xmW) + ((size_t)b * Cn + c0) * 64;
        for (int e = tid; e < 1024; e += 256) {
            int ci = e >> 6, i = e & 63;
            float acc = 0.f;
            const float* wc = w7 + (c0 + ci) * 7;
#pragma unroll
            for (int j = 0; j < 7; j++) {
                int ii = i + j - 3;
                if (ii >= 0 && ii < 64) acc += xm[ci * 64 + ii] * wc[j];
            }
            y[p][e] = acc;
        }
    }
    __syncthreads();
    for (int p = 0; p < 2; p++) {
        float s = 0.f, s2 = 0.f;
        for (int e = tid; e < 1024; e += 256) { float v = y[p][e]; s += v; s2 += v * v; }
        float2 r = block_sum2<256>(s, s2);
        float m = r.x * (1.f / 1024.f);
        float var = r.y * (1.f / 1024.f) - m * m;
        float inv = rsqrtf(fmaxf(var, 0.f) + 1e-5f);
        float* outp = (p == 0 ? xh : xw) + ((size_t)b * Cn + c0) * 64;
        for (int e = tid; e < 1024; e += 256) {
            int ci = e >> 6, i = e & 63;
            float v = (y[p][e] - m) * inv * gnw[c0 + ci] + gnb[c0 + ci];
            outp[ci * 64 + i] = v > 0.f ? v : 0.f;
        }
    }
}

__global__ void k_gate_norm1(const float* __restrict__ x, const float* __restrict__ xh,
                             const float* __restrict__ xw, const float* __restrict__ n1w,
                             const float* __restrict__ n1b, bf16* __restrict__ tn) {
    int blk = blockIdx.x;
    int b = blk >> 12, n = blk & 4095;
    int hh = n >> 6, ww = n & 63;
    int c = threadIdx.x;
    float v = x[(((size_t)b * Cn + c) * 64 + hh) * 64 + ww] *
              xh[((size_t)b * Cn + c) * 64 + hh] * xw[((size_t)b * Cn + c) * 64 + ww];
    float2 r = block_sum2<256>(v, v * v);
    float m = r.x * (1.f / 256.f), var = r.y * (1.f / 256.f) - m * m;
    float inv = rsqrtf(fmaxf(var, 0.f) + 1e-6f);
    tn[(size_t)blk * 256 + c] = f2b((v - m) * inv * n1w[c] + n1b[c]);
}

__global__ void k_red1(const bf16* __restrict__ tn, const float* __restrict__ rw,
                       const float* __restrict__ rb, float* __restrict__ red1) {
    int blk = blockIdx.x;
    int b = blk >> 8, c = blk & 255;
    int t = threadIdx.x;
    int yo = t >> 4, xo = t & 15;
    float acc = rb[c];
    const float* w = rw + c * 16;
    const bf16* base = tn + (size_t)b * Nn * Cn + c;
#pragma unroll
    for (int dy = 0; dy < 4; dy++)
#pragma unroll
        for (int dx = 0; dx < 4; dx++)
            acc += b2f(base[(size_t)((yo * 4 + dy) * 64 + xo * 4 + dx) * Cn]) * w[dy * 4 + dx];
    red1[(size_t)blk * 256 + t] = acc;
}

__global__ void k_red2(const float* __restrict__ red1, const float* __restrict__ rw,
                       const float* __restrict__ rb, float* __restrict__ red2) {
    int idx = blockIdx.x * 256 + threadIdx.x;
    int t = idx & 15, bc = idx >> 4;
    int c = bc & 255;
    int yo = t >> 2, xo = t & 3;
    float acc = rb[c];
    const float* w = rw + c * 16;
    const float* base = red1 + (size_t)bc * 256;
#pragma unroll
    for (int dy = 0; dy < 4; dy++)
#pragma unroll
        for (int dx = 0; dx < 4; dx++)
            acc += base[(yo * 4 + dy) * 16 + xo * 4 + dx] * w[dy * 4 + dx];
    red2[idx] = acc;
}

__global__ void k_dw3(const float* __restrict__ in, const float* __restrict__ w9,
                      const float* __restrict__ bb, float* __restrict__ outp) {
    int idx = blockIdx.x * 256 + threadIdx.x;
    int t = idx & 15, bc = idx >> 4, c = bc & 255;
    int y = t >> 2, x = t & 3;
    float acc = bb[c];
    const float* w = w9 + c * 9;
    const float* base = in + (size_t)bc * 16;
#pragma unroll
    for (int dy = -1; dy <= 1; dy++)
#pragma unroll
        for (int dx = -1; dx <= 1; dx++) {
            int yy = y + dy, xx = x + dx;
            if (yy >= 0 && yy < 4 && xx >= 0 && xx < 4)
                acc += base[yy * 4 + xx] * w[(dy + 1) * 3 + (dx + 1)];
        }
    outp[idx] = acc;
}

__global__ void k_conv1x1_ln(const float* __restrict__ dwr, const float* __restrict__ cw,
                             const float* __restrict__ cb, const float* __restrict__ naw,
                             const float* __restrict__ nab, float* __restrict__ xr) {
    int b = blockIdx.x >> 4, m = blockIdx.x & 15;
    int tid = threadIdx.x;
    __shared__ float in[256];
    for (int c = tid; c < 256; c += 128) in[c] = dwr[((size_t)b * Cn + c) * 16 + m];
    __syncthreads();
    float acc = cb[tid];
    const float* w = cw + tid * 256;
    for (int c = 0; c < 256; c++) acc += in[c] * w[c];
    float2 r = block_sum2<128>(acc, acc * acc);
    float mm = r.x * (1.f / 128.f), var = r.y * (1.f / 128.f) - mm * mm;
    float inv = rsqrtf(fmaxf(var, 0.f) + 1e-5f);
    float z = (acc - mm) * inv * naw[tid] + nab[tid];
    xr[(size_t)blockIdx.x * 128 + tid] = gelu_f(z);
}

__global__ void k_kv(const float* __restrict__ xr, const float* __restrict__ kw,
                     const float* __restrict__ vw, float* __restrict__ kbuf, float* __restrict__ v0) {
    int bm = blockIdx.x;
    int tid = threadIdx.x;
    __shared__ float in[128];
    if (tid < 128) in[tid] = xr[(size_t)bm * 128 + tid];
    __syncthreads();
    float acc = 0.f;
    for (int i = 0; i < 128; i++) acc += in[i] * vw[i * 256 + tid];
    v0[(size_t)bm * 256 + tid] = acc;
    if (tid < 128) {
        float ak = 0.f;
        for (int i = 0; i < 128; i++) ak += in[i] * kw[i * 128 + tid];
        kbuf[(size_t)bm * 128 + tid] = ak;
    }
}

__global__ void k_cpe(const float* __restrict__ v0, const float* __restrict__ cw,
                      const float* __restrict__ cb, float* __restrict__ v) {
    int idx = blockIdx.x * 256 + threadIdx.x;
    int c = idx & 255, bm = idx >> 8;
    int b = bm >> 4, m = bm & 15;
    int y = m >> 2, x = m & 3;
    float acc = v0[idx] + cb[c];
#pragma unroll
    for (int dy = -1; dy <= 1; dy++)
#pragma unroll
        for (int dx = -1; dx <= 1; dx++) {
            int yy = y + dy, xx = x + dx;
            if (yy >= 0 && yy < 4 && xx >= 0 && xx < 4)
                acc += v0[((size_t)b * 16 + yy * 4 + xx) * 256 + c] * cw[c * 9 + (dy + 1) * 3 + (dx + 1)];
        }
    v[idx] = acc;
}

__global__ void k_attn(const bf16* __restrict__ q, const float* __restrict__ kbuf,
                       const float* __restrict__ v, bf16* o) {
    int blk = blockIdx.x;
    int chunk = blk & 7, bh = blk >> 3;
    int h = bh & 7, b = bh >> 3;
    __shared__ float ks[16][16];
    __shared__ float vs[16][32];
    int tid = threadIdx.x;
    {
        int m = tid >> 4, d = tid & 15;
        ks[m][d] = kbuf[((size_t)(b * 16 + m)) * 128 + h * 16 + d];
    }
    for (int i = tid; i < 512; i += 256) {
        int m = i >> 5, e = i & 31;
        vs[m][e] = v[((size_t)(b * 16 + m)) * 256 + h * 32 + e];
    }
    __syncthreads();
    for (int it = 0; it < 2; it++) {
        int n = chunk * 512 + it * 256 + tid;
        const bf16* qp = q + ((size_t)b * Nn + n) * 128 + h * 16;
        float qr[16];
#pragma unroll
        for (int d = 0; d < 16; d++) qr[d] = b2f(qp[d]);
        float sc[16];
        float mx = -1e30f;
#pragma unroll
        for (int m = 0; m < 16; m++) {
            float s = 0.f;
#pragma unroll
            for (int d = 0; d < 16; d++) s += qr[d] * ks[m][d];
            s *= 0.25f;
            sc[m] = s;
            mx = fmaxf(mx, s);
        }
        float den = 0.f;
#pragma unroll
        for (int m = 0; m < 16; m++) { sc[m] = expf(sc[m] - mx); den += sc[m]; }
        float rden = 1.f / den;
        float ov[32];
#pragma unroll
        for (int e = 0; e < 32; e++) ov[e] = 0.f;
#pragma unroll
        for (int m = 0; m < 16; m++) {
            float p = sc[m] * rden;
#pragma unroll
            for (int e = 0; e < 32; e++) ov[e] += p * vs[m][e];
        }
        bf16* op = o + ((size_t)b * Nn + n) * 256 + h * 32;
#pragma unroll
        for (int e = 0; e < 32; e++) op[e] = f2b(ov[e]);
    }
}

// ---- LN of (po + residual) -> tn2 ----
__global__ void k_ln_res(const bf16* __restrict__ po, const float* __restrict__ x,
                         const float* __restrict__ xh, const float* __restrict__ xw,
                         const float* __restrict__ n2w, const float* __restrict__ n2b,
                         bf16* __restrict__ tn2) {
    __shared__ float t1s[16][256];
    int tid = threadIdx.x, c = tid;
    size_t row0 = (size_t)blockIdx.x * 16;
    int b = (int)(row0 >> 12);
    int n0 = (int)(row0 & 4095);
    int hh = n0 >> 6, w0 = n0 & 63;
    float hg = xh[((size_t)b * 256 + c) * 64 + hh];
    const float* xp = x + (((size_t)b * 256 + c) * 64 + hh) * 64 + w0;
    const float* wp = xw + ((size_t)b * 256 + c) * 64 + w0;
    for (int r = 0; r < 16; r++)
        t1s[r][c] = b2f(po[(row0 + r) * 256 + c]) + xp[r] * hg * wp[r];
    __syncthreads();
    int wv = tid >> 6, lane = tid & 63;
    float nw[4], nb[4];
#pragma unroll
    for (int k2 = 0; k2 < 4; k2++) { nw[k2] = n2w[lane + k2 * 64]; nb[k2] = n2b[lane + k2 * 64]; }
    for (int rr = 0; rr < 4; rr++) {
        int r = wv * 4 + rr;
        float s = 0.f, s2 = 0.f;
#pragma unroll
        for (int k2 = 0; k2 < 4; k2++) { float v = t1s[r][lane + k2 * 64]; s += v; s2 += v * v; }
#pragma unroll
        for (int off2 = 32; off2; off2 >>= 1) { s += __shfl_down(s, off2); s2 += __shfl_down(s2, off2); }
        s = __shfl(s, 0); s2 = __shfl(s2, 0);
        float m = s * (1.f / 256.f), var = s2 * (1.f / 256.f) - m * m;
        float inv = rsqrtf(fmaxf(var, 0.f) + 1e-6f);
#pragma unroll
        for (int k2 = 0; k2 < 4; k2++) {
            int cc = lane + k2 * 64;
            float v = t1s[r][cc];
            tn2[(row0 + r) * 256 + cc] = f2b((v - m) * inv * nw[k2] + nb[k2]);
        }
    }
}

// ---- in-place LN over 512 cols (gnorm) ----
__global__ void k_ln512(bf16* __restrict__ x2, const float* __restrict__ gnw,
                        const float* __restrict__ gnb) {
    __shared__ float s[16][512];
    int tid = threadIdx.x;
    size_t row0 = (size_t)blockIdx.x * 16;
    for (int i = tid; i < 16 * 512; i += 256) s[i >> 9][i & 511] = b2f(x2[row0 * 512 + i]);
    __syncthreads();
    int wv = tid >> 6, lane = tid & 63;
    float nw[8], nb[8];
#pragma unroll
    for (int k2 = 0; k2 < 8; k2++) { nw[k2] = gnw[lane + k2 * 64]; nb[k2] = gnb[lane + k2 * 64]; }
    for (int rr = 0; rr < 4; rr++) {
        int r = wv * 4 + rr;
        float a = 0.f, a2 = 0.f;
#pragma unroll
        for (int k2 = 0; k2 < 8; k2++) { float v = s[r][lane + k2 * 64]; a += v; a2 += v * v; }
#pragma unroll
        for (int off2 = 32; off2; off2 >>= 1) { a += __shfl_down(a, off2); a2 += __shfl_down(a2, off2); }
        a = __shfl(a, 0); a2 = __shfl(a2, 0);
        float m = a * (1.f / 512.f), var = a2 * (1.f / 512.f) - m * m;
        float inv = rsqrtf(fmaxf(var, 0.f) + 1e-5f);
#pragma unroll
        for (int k2 = 0; k2 < 8; k2++) {
            int e = lane + k2 * 64;
            float v = (s[r][e] - m) * inv * nw[k2] + nb[k2];
            x2[(row0 + r) * 512 + e] = f2b(v);
        }
    }
}

__global__ void k_gatec(const bf16* __restrict__ x2n, const float* __restrict__ gw,
                        const float* __restrict__ gb, bf16* __restrict__ x1io) {
    size_t idx = (size_t)blockIdx.x * 256 + threadIdx.x;
    int c = (int)(idx & 511);
    size_t bn = idx >> 9;
    int n = (int)(bn & 4095);
    size_t b = bn >> 12;
    int y = n >> 6, x = n & 63;
    float acc = gb[c];
    const float* w = gw + c * 9;
#pragma unroll
    for (int dy = -1; dy <= 1; dy++)
#pragma unroll
        for (int dx = -1; dx <= 1; dx++) {
            int yy = y + dy, xx = x + dx;
            if (yy >= 0 && yy < 64 && xx >= 0 && xx < 64)
                acc += b2f(x2n[(b * Nn + yy * 64 + xx) * 512 + c]) * w[(dy + 1) * 3 + (dx + 1)];
        }
    float g = b2f(x1io[idx]) * acc;
    x1io[idx] = f2b(g);
}

extern "C" void kernel_launch(void* const* d_in, const int* in_sizes, int n_in,
                              void* d_out, int out_size, void* d_ws, size_t ws_size,
                              hipStream_t stream) {
    const float* x = (const float*)d_in[0];
    const float* sda_conv_w = (const float*)d_in[1];
    const float* sda_gn_w = (const float*)d_in[2];
    const float* sda_gn_b = (const float*)d_in[3];
    const float* norm1_w = (const float*)d_in[4];
    const float* norm1_b = (const float*)d_in[5];
    const float* red_w = (const float*)d_in[6];
    const float* red_b = (const float*)d_in[7];
    const float* dw_w = (const float*)d_in[8];
    const float* dw_b = (const float*)d_in[9];
    const float* conv_w = (const float*)d_in[10];
    const float* conv_b = (const float*)d_in[11];
    const float* na_w = (const float*)d_in[12];
    const float* na_b = (const float*)d_in[13];
    const float* q_w = (const float*)d_in[14];
    const float* k_w = (const float*)d_in[15];
    const float* v_w = (const float*)d_in[16];
    const float* cpe_w = (const float*)d_in[17];
    const float* cpe_b = (const float*)d_in[18];
    const float* proj_w = (const float*)d_in[19];
    const float* proj_b = (const float*)d_in[20];
    const float* norm2_w = (const float*)d_in[21];
    const float* norm2_b = (const float*)d_in[22];
    const float* fc1_w = (const float*)d_in[23];
    const float* fc1_b = (const float*)d_in[24];
    const float* gnorm_w = (const float*)d_in[25];
    const float* gnorm_b = (const float*)d_in[26];
    const float* gconv_w = (const float*)d_in[27];
    const float* gconv_b = (const float*)d_in[28];
    const float* fc2_w = (const float*)d_in[29];
    const float* fc2_b = (const float*)d_in[30];
    float* outp = (float*)d_out;

    char* ws = (char*)d_ws;
    size_t off = 0;
    auto alloc = [&](size_t bytes) -> char* {
        char* p = ws + off;
        off += (bytes + 255) & ~(size_t)255;
        return p;
    };
    // ws ~177 MB (round-4 footprint + ~1 MB weights; 176 MB proven safe).
    bf16* po = (bf16*)alloc((size_t)Mtot * Cn * 2);       // 33.5 MB
    char* arena2 = alloc((size_t)Mtot * HALFn * 2);       // qb then x1 (67 MB)
    char* arena3 = alloc((size_t)Mtot * HALFn * 2);       // red1 then x2b (67 MB)
    float* xmH = (float*)alloc((size_t)Bn * Cn * 64 * 4);
    float* xmW = (float*)alloc((size_t)Bn * Cn * 64 * 4);
    float* xh = (float*)alloc((size_t)Bn * Cn * 64 * 4);
    float* xw = (float*)alloc((size_t)Bn * Cn * 64 * 4);
    float* red2 = (float*)alloc((size_t)Bn * Cn * 16 * 4);
    float* dwr = (float*)alloc((size_t)Bn * Cn * 16 * 4);
    float* xr = (float*)alloc((size_t)Bn * 16 * 128 * 4);
    float* kb = (float*)alloc((size_t)Bn * 16 * 128 * 4);
    float* v0 = (float*)alloc((size_t)Bn * 16 * 256 * 4);
    float* vb = (float*)alloc((size_t)Bn * 16 * 256 * 4);
    bf16* qwT = (bf16*)alloc((size_t)128 * 256 * 2);   // [N][K] bf16 weights
    bf16* pwT = (bf16*)alloc((size_t)256 * 256 * 2);
    bf16* f1T = (bf16*)alloc((size_t)1024 * 256 * 2);
    bf16* f2T = (bf16*)alloc((size_t)256 * 512 * 2);

    bf16* tn = (bf16*)d_out;       // norm1 out -> o -> tn2, dies before final write
    bf16* qb = (bf16*)arena2;      // dies after k_attn
    bf16* x1 = (bf16*)arena2;      // born at gemm_fc1
    float* red1 = (float*)arena3;  // dies after k_red2
    bf16* x2b = (bf16*)arena3;     // born at gemm_fc1 (pre-LN, LN'd in place)

    // weight conversion (transpose to [N][K] bf16)
    k_cvtw<<<(256 / 32) * (128 / 32), 256, 0, stream>>>(q_w, qwT, 256, 128);
    k_cvtw<<<(256 / 32) * (256 / 32), 256, 0, stream>>>(proj_w, pwT, 256, 256);
    k_cvtw<<<(256 / 32) * (1024 / 32), 256, 0, stream>>>(fc1_w, f1T, 256, 1024);
    k_cvtw<<<(512 / 32) * (256 / 32), 256, 0, stream>>>(fc2_w, f2T, 512, 256);

    k_pool<<<Bn * Cn, 256, 0, stream>>>(x, xmH, xmW);
    k_sda<<<Bn * 16, 256, 0, stream>>>(xmH, xmW, sda_conv_w, sda_gn_w, sda_gn_b, xh, xw);
    k_gate_norm1<<<Bn * Nn, 256, 0, stream>>>(x, xh, xw, norm1_w, norm1_b, tn);
    k_red1<<<Bn * Cn, 256, 0, stream>>>(tn, red_w, red_b, red1);
    k_red2<<<256, 256, 0, stream>>>(red1, red_w, red_b, red2);
    k_dw3<<<256, 256, 0, stream>>>(red2, dw_w, dw_b, dwr);
    k_conv1x1_ln<<<Bn * 16, 128, 0, stream>>>(dwr, conv_w, conv_b, na_w, na_b, xr);
    k_kv<<<Bn * 16, 256, 0, stream>>>(xr, k_w, v_w, kb, v0);
    k_cpe<<<256, 256, 0, stream>>>(v0, cpe_w, cpe_b, vb);
    gemm_q<<<(Mtot / 64) * 2, 256, 0, stream>>>(tn, qwT, qb);
    k_attn<<<Bn * NHn * 8, 256, 0, stream>>>(qb, kb, vb, tn);  // o overwrites tn region
    gemm_proj<<<(Mtot / 64) * 4, 256, 0, stream>>>(tn, pwT, proj_b, po);
    k_ln_res<<<Mtot / 16, 256, 0, stream>>>(po, x, xh, xw, norm2_w, norm2_b, tn);  // tn2 over o
    gemm_fc1<<<(Mtot / 64) * 16, 256, 0, stream>>>(tn, f1T, fc1_b, x1, x2b);
    k_ln512<<<Mtot / 16, 256, 0, stream>>>(x2b, gnorm_w, gnorm_b);
    k_gatec<<<(Mtot * HALFn) / 256, 256, 0, stream>>>(x2b, gconv_w, gconv_b, x1);
    gemm_fc2<<<(Mtot / 64) * 4, 256, 0, stream>>>(x1, f2T, fc2_b, po, x, xh, xw, outp);
}

// Round 6
// 1352.179 us; speedup vs baseline: 1.7192x; 1.0060x over previous
//
#include <hip/hip_runtime.h>
#include <hip/hip_bf16.h>
#include <cmath>

#define DEV __device__ __forceinline__

constexpr int Bn = 16, Cn = 256, Nn = 4096;
constexpr int NHn = 8, CRn = 128, HALFn = 512;
constexpr int Mtot = Bn * Nn;  // 65536 token rows

typedef __hip_bfloat16 bf16;
typedef __attribute__((ext_vector_type(8))) short bf16x8;
typedef __attribute__((ext_vector_type(4))) float f32x4;

DEV float b2f(bf16 v) { return __bfloat162float(v); }
DEV bf16 f2b(float v) { return __float2bfloat16(v); }
DEV float gelu_f(float x) { return 0.5f * x * (1.0f + erff(x * 0.70710678118654752f)); }

template <int NT>
DEV float2 block_sum2(float a, float b) {
    __shared__ float sh[2 * NT / 64];
    __syncthreads();
    int lane = threadIdx.x & 63, wv = threadIdx.x >> 6;
#pragma unroll
    for (int off = 32; off; off >>= 1) { a += __shfl_down(a, off); b += __shfl_down(b, off); }
    if (lane == 0) { sh[wv * 2] = a; sh[wv * 2 + 1] = b; }
    __syncthreads();
    float ta = 0.f, tb = 0.f;
#pragma unroll
    for (int i = 0; i < NT / 64; i++) { ta += sh[i * 2]; tb += sh[i * 2 + 1]; }
    return make_float2(ta, tb);
}

// ================= MFMA GEMM machinery =================
constexpr int LDP = 136;

DEV void stage64(const bf16* __restrict__ g, int stride, short* lds) {
    int t = threadIdx.x;
    int r = t >> 2, seg = t & 3;
    const uint4* src = (const uint4*)(g + (size_t)r * stride + seg * 32);
    uint4* dst = (uint4*)(lds + r * LDP + seg * 32);
#pragma unroll
    for (int i = 0; i < 4; i++) dst[i] = src[i];
}

DEV void compute_chunk(const short* lA, const short* lW, f32x4* acc) {
    int lane = threadIdx.x & 63;
    int w = threadIdx.x >> 6;
    const short* pa = lA + (w * 16 + (lane & 15)) * LDP + (lane >> 4) * 8;
    const short* pb = lW + (lane & 15) * LDP + (lane >> 4) * 8;
#pragma unroll
    for (int kt = 0; kt < 4; kt++) {
        bf16x8 a = *(const bf16x8*)(pa + kt * 32);
#pragma unroll
        for (int nt = 0; nt < 4; nt++) {
            bf16x8 b = *(const bf16x8*)(pb + nt * 16 * LDP + kt * 32);
            acc[nt] = __builtin_amdgcn_mfma_f32_16x16x32_bf16(a, b, acc[nt], 0, 0, 0);
        }
    }
}

template <int K>
DEV void gemm_main(const bf16* __restrict__ A, const bf16* __restrict__ Wt,
                   int mblk, int nblk, short* lA, short* lW, f32x4* acc) {
#pragma unroll
    for (int nt = 0; nt < 4; nt++)
#pragma unroll
        for (int i = 0; i < 4; i++) acc[nt][i] = 0.f;
    for (int kc = 0; kc < K / 128; kc++) {
        if (kc) __syncthreads();
        stage64(A + (size_t)mblk * 64 * K + kc * 128, K, lA);
        stage64(Wt + (size_t)nblk * 64 * K + kc * 128, K, lW);
        __syncthreads();
        compute_chunk(lA, lW, acc);
    }
}

__global__ void k_cvtw(const float* __restrict__ W, bf16* __restrict__ Wt, int K, int N) {
    __shared__ float t[32][33];
    int ntn = N >> 5;
    int bx = blockIdx.x % ntn, by = blockIdx.x / ntn;
    int tx = threadIdx.x & 31, ty = threadIdx.x >> 5;
#pragma unroll
    for (int i = 0; i < 4; i++)
        t[ty + i * 8][tx] = W[(size_t)(by * 32 + ty + i * 8) * N + bx * 32 + tx];
    __syncthreads();
#pragma unroll
    for (int i = 0; i < 4; i++)
        Wt[(size_t)(bx * 32 + ty + i * 8) * K + by * 32 + tx] = f2b(t[tx][ty + i * 8]);
}

__global__ void gemm_q(const bf16* __restrict__ A, const bf16* __restrict__ Wt,
                       bf16* __restrict__ out) {
    __shared__ short lA[64 * LDP], lW[64 * LDP];
    int mblk = blockIdx.x >> 1, nblk = blockIdx.x & 1;
    f32x4 acc[4];
    gemm_main<256>(A, Wt, mblk, nblk, lA, lW, acc);
    int lane = threadIdx.x & 63, w = threadIdx.x >> 6, m16 = lane & 15, quad = lane >> 4;
    size_t rowb = (size_t)mblk * 64 + w * 16 + quad * 4;
#pragma unroll
    for (int nt = 0; nt < 4; nt++) {
        int col = nblk * 64 + nt * 16 + m16;
#pragma unroll
        for (int reg = 0; reg < 4; reg++) out[(rowb + reg) * 128 + col] = f2b(acc[nt][reg]);
    }
}

__global__ void gemm_proj(const bf16* __restrict__ A, const bf16* __restrict__ Wt,
                          const float* __restrict__ pb, bf16* __restrict__ out) {
    __shared__ short lA[64 * LDP], lW[64 * LDP];
    int mblk = blockIdx.x >> 2, nblk = blockIdx.x & 3;
    f32x4 acc[4];
    gemm_main<256>(A, Wt, mblk, nblk, lA, lW, acc);
    int lane = threadIdx.x & 63, w = threadIdx.x >> 6, m16 = lane & 15, quad = lane >> 4;
    size_t rowb = (size_t)mblk * 64 + w * 16 + quad * 4;
#pragma unroll
    for (int nt = 0; nt < 4; nt++) {
        int col = nblk * 64 + nt * 16 + m16;
        float bv = pb[col];
#pragma unroll
        for (int reg = 0; reg < 4; reg++) out[(rowb + reg) * 256 + col] = f2b(acc[nt][reg] + bv);
    }
}

__global__ void gemm_fc1(const bf16* __restrict__ A, const bf16* __restrict__ Wt,
                         const float* __restrict__ fb, bf16* __restrict__ x1,
                         bf16* __restrict__ x2b) {
    __shared__ short lA[64 * LDP], lW[64 * LDP];
    int mblk = blockIdx.x >> 4, nblk = blockIdx.x & 15;
    f32x4 acc[4];
    gemm_main<256>(A, Wt, mblk, nblk, lA, lW, acc);
    int tid = threadIdx.x;
    int lane = tid & 63, w = tid >> 6, m16 = lane & 15, quad = lane >> 4;
    __syncthreads();
    bf16* ldsO = (bf16*)lA;
    int rl0 = w * 16 + quad * 4;
#pragma unroll
    for (int nt = 0; nt < 4; nt++) {
        int col = nblk * 64 + nt * 16 + m16;
        float bv = fb[col];
#pragma unroll
        for (int reg = 0; reg < 4; reg++)
            ldsO[(rl0 + reg) * 72 + nt * 16 + m16] = f2b(gelu_f(acc[nt][reg] + bv));
    }
    __syncthreads();
    int lm = tid >> 2, seg = tid & 3;
    int colg = nblk * 64 + seg * 16;
    bf16* dst = (colg < 512) ? (x1 + (size_t)(mblk * 64 + lm) * 512 + colg)
                             : (x2b + (size_t)(mblk * 64 + lm) * 512 + colg - 512);
    const uint4* s = (const uint4*)(ldsO + lm * 72 + seg * 16);
    uint4* d = (uint4*)dst;
    d[0] = s[0];
    d[1] = s[1];
}

__global__ void gemm_fc2(const bf16* __restrict__ A, const bf16* __restrict__ Wt,
                         const float* __restrict__ fb, const bf16* __restrict__ po,
                         const float* __restrict__ x, const float* __restrict__ xh,
                         const float* __restrict__ xw, float* __restrict__ outp) {
    __shared__ short lA[64 * LDP], lW[64 * LDP];
    int mblk = blockIdx.x >> 2, nblk = blockIdx.x & 3;
    f32x4 acc[4];
    gemm_main<512>(A, Wt, mblk, nblk, lA, lW, acc);
    int tid = threadIdx.x;
    int lane = tid & 63, w = tid >> 6, m16 = lane & 15, quad = lane >> 4;
    __syncthreads();
    float* ldsF = (float*)lA;
    int b = mblk >> 6;
    int hh = mblk & 63;
    int n0 = hh * 64;
    int rl0 = w * 16 + quad * 4;
#pragma unroll
    for (int nt = 0; nt < 4; nt++) {
        int c = nblk * 64 + nt * 16 + m16;
        float bv = fb[c];
        float hg = xh[((size_t)b * 256 + c) * 64 + hh];
        const float* xp = x + (((size_t)b * 256 + c) * 64 + hh) * 64 + rl0;
        const float* wp = xw + ((size_t)b * 256 + c) * 64 + rl0;
        const bf16* pp = po + ((size_t)mblk * 64 + rl0) * 256 + c;
#pragma unroll
        for (int reg = 0; reg < 4; reg++) {
            float v = acc[nt][reg] + bv + b2f(pp[reg * 256]) + xp[reg] * hg * wp[reg];
            ldsF[(rl0 + reg) * 65 + nt * 16 + m16] = v;
        }
    }
    __syncthreads();
    int cl = tid >> 2, ms = tid & 3;
    size_t ob = ((size_t)b * 256 + nblk * 64 + cl) * 4096 + n0 + ms * 16;
#pragma unroll
    for (int g2 = 0; g2 < 4; g2++) {
        float4 v4 = make_float4(ldsF[(ms * 16 + g2 * 4 + 0) * 65 + cl],
                                ldsF[(ms * 16 + g2 * 4 + 1) * 65 + cl],
                                ldsF[(ms * 16 + g2 * 4 + 2) * 65 + cl],
                                ldsF[(ms * 16 + g2 * 4 + 3) * 65 + cl]);
        *(float4*)(outp + ob + g2 * 4) = v4;
    }
}

// ================= non-GEMM kernels =================

__global__ void k_pool(const float* __restrict__ x, float* __restrict__ xmH, float* __restrict__ xmW) {
    __shared__ float t[4096];
    int blk = blockIdx.x;
    const float* xp = x + (size_t)blk * 4096;
    int tid = threadIdx.x;
    for (int k = 0; k < 16; k++) t[tid + k * 256] = xp[tid + k * 256];
    __syncthreads();
    if (tid < 64) {
        float rs = 0.f, cs = 0.f;
        for (int w = 0; w < 64; w++) {
            int ws = (w + tid) & 63;
            rs += t[tid * 64 + ws];
            cs += t[w * 64 + tid];
        }
        xmH[(size_t)blk * 64 + tid] = rs * (1.f / 64.f);
        xmW[(size_t)blk * 64 + tid] = cs * (1.f / 64.f);
    }
}

__global__ void k_sda(const float* __restrict__ xmH, const float* __restrict__ xmW,
                      const float* __restrict__ w7, const float* __restrict__ gnw,
                      const float* __restrict__ gnb, float* __restrict__ xh, float* __restrict__ xw) {
    int b = blockIdx.x >> 4, grp = blockIdx.x & 15;
    int c0 = grp * 16;
    int tid = threadIdx.x;
    __shared__ float y[2][1024];
    for (int p = 0; p < 2; p++) {
        const float* xm = (p == 0 ? xmH : xmW) + ((size_t)b * Cn + c0) * 64;
        for (int e = tid; e < 1024; e += 256) {
            int ci = e >> 6, i = e & 63;
            float acc = 0.f;
            const float* wc = w7 + (c0 + ci) * 7;
#pragma unroll
            for (int j = 0; j < 7; j++) {
                int ii = i + j - 3;
                if (ii >= 0 && ii < 64) acc += xm[ci * 64 + ii] * wc[j];
            }
            y[p][e] = acc;
        }
    }
    __syncthreads();
    for (int p = 0; p < 2; p++) {
        float s = 0.f, s2 = 0.f;
        for (int e = tid; e < 1024; e += 256) { float v = y[p][e]; s += v; s2 += v * v; }
        float2 r = block_sum2<256>(s, s2);
        float m = r.x * (1.f / 1024.f);
        float var = r.y * (1.f / 1024.f) - m * m;
        float inv = rsqrtf(fmaxf(var, 0.f) + 1e-5f);
        float* outp = (p == 0 ? xh : xw) + ((size_t)b * Cn + c0) * 64;
        for (int e = tid; e < 1024; e += 256) {
            int ci = e >> 6, i = e & 63;
            float v = (y[p][e] - m) * inv * gnw[c0 + ci] + gnb[c0 + ci];
            outp[ci * 64 + i] = v > 0.f ? v : 0.f;
        }
    }
}

// ---- K2 rewrite: block = (b, hh). Coalesced x/xw row loads; LN over c in LDS. ----
__global__ void k_gate_norm1(const float* __restrict__ x, const float* __restrict__ xh,
                             const float* __restrict__ xw, const float* __restrict__ n1w,
                             const float* __restrict__ n1b, bf16* __restrict__ tn) {
    __shared__ float xs[256][65];
    __shared__ float ps[64][4], pq[64][4];
    int b = blockIdx.x >> 6, hh = blockIdx.x & 63;
    int c = threadIdx.x;
    float hx = xh[((size_t)b * 256 + c) * 64 + hh];
    const float* xrow = x + (((size_t)b * 256 + c) * 64 + hh) * 64;
    const float* wrow = xw + ((size_t)b * 256 + c) * 64;
#pragma unroll
    for (int w = 0; w < 64; w += 4) {
        float4 xv = *(const float4*)(xrow + w);
        float4 wv = *(const float4*)(wrow + w);
        xs[c][w + 0] = xv.x * hx * wv.x;
        xs[c][w + 1] = xv.y * hx * wv.y;
        xs[c][w + 2] = xv.z * hx * wv.z;
        xs[c][w + 3] = xv.w * hx * wv.w;
    }
    __syncthreads();
    int p = c >> 6, ww = c & 63;  // wave p handles channel range [p*64, p*64+64)
    float s = 0.f, s2 = 0.f;
    for (int i = 0; i < 64; i++) { float v = xs[p * 64 + i][ww]; s += v; s2 += v * v; }
    ps[ww][p] = s;
    pq[ww][p] = s2;
    __syncthreads();
    float st = 0.f, qt = 0.f;
#pragma unroll
    for (int k = 0; k < 4; k++) { st += ps[ww][k]; qt += pq[ww][k]; }
    float m = st * (1.f / 256.f), var = qt * (1.f / 256.f) - m * m;
    float inv = rsqrtf(fmaxf(var, 0.f) + 1e-6f);
    size_t orow = ((size_t)b * 4096 + hh * 64 + ww) * 256 + p * 64;
    for (int j = 0; j < 64; j += 8) {
        uint4 u;
        short* ts = (short*)&u;
#pragma unroll
        for (int jj = 0; jj < 8; jj++) {
            int cc = p * 64 + j + jj;
            float v = (xs[cc][ww] - m) * inv * n1w[cc] + n1b[cc];
            bf16 h = f2b(v);
            ts[jj] = *(short*)&h;
        }
        *(uint4*)(tn + orow + j) = u;
    }
}

// ---- K4 rewrite: block = (b, yo, wq). Lane = c -> coalesced tn reads. ----
__global__ void k_red1(const bf16* __restrict__ tn, const float* __restrict__ rw,
                       const float* __restrict__ rb, float* __restrict__ red1) {
    int blk = blockIdx.x;
    int b = blk >> 6, yo = (blk >> 2) & 15, wq = blk & 3;
    int c = threadIdx.x;
    float wreg[16];
#pragma unroll
    for (int j = 0; j < 16; j++) wreg[j] = rw[c * 16 + j];
    float acc[4];
#pragma unroll
    for (int j = 0; j < 4; j++) acc[j] = rb[c];
    for (int dy = 0; dy < 4; dy++) {
        int hh = yo * 4 + dy;
        const bf16* row = tn + ((size_t)b * 4096 + hh * 64 + wq * 16) * 256 + c;
#pragma unroll
        for (int wl = 0; wl < 16; wl++) {
            float v = b2f(row[wl * 256]);
            acc[wl >> 2] += v * wreg[dy * 4 + (wl & 3)];
        }
    }
    float* dst = red1 + ((size_t)b * 256 + c) * 256 + yo * 16 + wq * 4;
    *(float4*)dst = make_float4(acc[0], acc[1], acc[2], acc[3]);
}

__global__ void k_red2(const float* __restrict__ red1, const float* __restrict__ rw,
                       const float* __restrict__ rb, float* __restrict__ red2) {
    int idx = blockIdx.x * 256 + threadIdx.x;
    int t = idx & 15, bc = idx >> 4;
    int c = bc & 255;
    int yo = t >> 2, xo = t & 3;
    float acc = rb[c];
    const float* w = rw + c * 16;
    const float* base = red1 + (size_t)bc * 256;
#pragma unroll
    for (int dy = 0; dy < 4; dy++)
#pragma unroll
        for (int dx = 0; dx < 4; dx++)
            acc += base[(yo * 4 + dy) * 16 + xo * 4 + dx] * w[dy * 4 + dx];
    red2[idx] = acc;
}

__global__ void k_dw3(const float* __restrict__ in, const float* __restrict__ w9,
                      const float* __restrict__ bb, float* __restrict__ outp) {
    int idx = blockIdx.x * 256 + threadIdx.x;
    int t = idx & 15, bc = idx >> 4, c = bc & 255;
    int y = t >> 2, x = t & 3;
    float acc = bb[c];
    const float* w = w9 + c * 9;
    const float* base = in + (size_t)bc * 16;
#pragma unroll
    for (int dy = -1; dy <= 1; dy++)
#pragma unroll
        for (int dx = -1; dx <= 1; dx++) {
            int yy = y + dy, xx = x + dx;
            if (yy >= 0 && yy < 4 && xx >= 0 && xx < 4)
                acc += base[yy * 4 + xx] * w[(dy + 1) * 3 + (dx + 1)];
        }
    outp[idx] = acc;
}

__global__ void k_conv1x1_ln(const float* __restrict__ dwr, const float* __restrict__ cw,
                             const float* __restrict__ cb, const float* __restrict__ naw,
                             const float* __restrict__ nab, float* __restrict__ xr) {
    int b = blockIdx.x >> 4, m = blockIdx.x & 15;
    int tid = threadIdx.x;
    __shared__ float in[256];
    for (int c = tid; c < 256; c += 128) in[c] = dwr[((size_t)b * Cn + c) * 16 + m];
    __syncthreads();
    float acc = cb[tid];
    const float* w = cw + tid * 256;
    for (int c = 0; c < 256; c++) acc += in[c] * w[c];
    float2 r = block_sum2<128>(acc, acc * acc);
    float mm = r.x * (1.f / 128.f), var = r.y * (1.f / 128.f) - mm * mm;
    float inv = rsqrtf(fmaxf(var, 0.f) + 1e-5f);
    float z = (acc - mm) * inv * naw[tid] + nab[tid];
    xr[(size_t)blockIdx.x * 128 + tid] = gelu_f(z);
}

__global__ void k_kv(const float* __restrict__ xr, const float* __restrict__ kw,
                     const float* __restrict__ vw, float* __restrict__ kbuf, float* __restrict__ v0) {
    int bm = blockIdx.x;
    int tid = threadIdx.x;
    __shared__ float in[128];
    if (tid < 128) in[tid] = xr[(size_t)bm * 128 + tid];
    __syncthreads();
    float acc = 0.f;
    for (int i = 0; i < 128; i++) acc += in[i] * vw[i * 256 + tid];
    v0[(size_t)bm * 256 + tid] = acc;
    if (tid < 128) {
        float ak = 0.f;
        for (int i = 0; i < 128; i++) ak += in[i] * kw[i * 128 + tid];
        kbuf[(size_t)bm * 128 + tid] = ak;
    }
}

__global__ void k_cpe(const float* __restrict__ v0, const float* __restrict__ cw,
                      const float* __restrict__ cb, float* __restrict__ v) {
    int idx = blockIdx.x * 256 + threadIdx.x;
    int c = idx & 255, bm = idx >> 8;
    int b = bm >> 4, m = bm & 15;
    int y = m >> 2, x = m & 3;
    float acc = v0[idx] + cb[c];
#pragma unroll
    for (int dy = -1; dy <= 1; dy++)
#pragma unroll
        for (int dx = -1; dx <= 1; dx++) {
            int yy = y + dy, xx = x + dx;
            if (yy >= 0 && yy < 4 && xx >= 0 && xx < 4)
                acc += v0[((size_t)b * 16 + yy * 4 + xx) * 256 + c] * cw[c * 9 + (dy + 1) * 3 + (dx + 1)];
        }
    v[idx] = acc;
}

// ---- K10 rewrite: block = (b, 64-row chunk), all heads; fully coalesced q/o. ----
// LDS padding chosen so banks spread: ks2 row 260 (h*4 mod 32 distinct),
// vs2 row 516, qs row 136 shorts, os row 264 shorts.
__global__ void k_attn(const bf16* __restrict__ q, const float* __restrict__ kbuf,
                       const float* __restrict__ v, bf16* o) {
    __shared__ float ks2[8 * 260];
    __shared__ float vs2[8 * 516];
    __shared__ short qs[64 * 136];
    __shared__ short os[64 * 264];
    int tid = threadIdx.x;
    int b = blockIdx.x >> 6, chunk = blockIdx.x & 63;
    int n0 = chunk * 64;
    const float* kbp = kbuf + (size_t)b * 2048;
    for (int i = tid; i < 2048; i += 256) {
        int m = i >> 7, rem = i & 127, h = rem >> 4, d = rem & 15;
        ks2[h * 260 + m * 16 + d] = kbp[i];
    }
    const float* vbp = v + (size_t)b * 4096;
    for (int i = tid; i < 4096; i += 256) {
        int m = i >> 8, rem = i & 255, h = rem >> 5, e = rem & 31;
        vs2[h * 516 + m * 32 + e] = vbp[i];
    }
    {
        int r = tid >> 2, seg = tid & 3;
        const uint4* src = (const uint4*)(q + ((size_t)b * 4096 + n0 + r) * 128 + seg * 32);
        uint4* dst = (uint4*)(qs + r * 136 + seg * 32);
#pragma unroll
        for (int i = 0; i < 4; i++) dst[i] = src[i];
    }
    __syncthreads();
#pragma unroll
    for (int it = 0; it < 2; it++) {
        int task = it * 256 + tid;
        int row = task >> 3, h = task & 7;
        const short* qp = qs + row * 136 + h * 16;
        float qr[16];
#pragma unroll
        for (int d = 0; d < 16; d++) qr[d] = b2f(*(const bf16*)(qp + d));
        const float* kh = ks2 + h * 260;
        float sc[16];
        float mx = -1e30f;
#pragma unroll
        for (int m = 0; m < 16; m++) {
            float s = 0.f;
#pragma unroll
            for (int d = 0; d < 16; d++) s += qr[d] * kh[m * 16 + d];
            s *= 0.25f;
            sc[m] = s;
            mx = fmaxf(mx, s);
        }
        float den = 0.f;
#pragma unroll
        for (int m = 0; m < 16; m++) { sc[m] = expf(sc[m] - mx); den += sc[m]; }
        float rden = 1.f / den;
        const float* vh = vs2 + h * 516;
        float ov[32];
#pragma unroll
        for (int e = 0; e < 32; e++) ov[e] = 0.f;
#pragma unroll
        for (int m = 0; m < 16; m++) {
            float p = sc[m] * rden;
#pragma unroll
            for (int e = 0; e < 32; e++) ov[e] += p * vh[m * 32 + e];
        }
        short* op = os + row * 264 + h * 32;
#pragma unroll
        for (int e = 0; e < 32; e++) {
            bf16 hv = f2b(ov[e]);
            op[e] = *(short*)&hv;
        }
    }
    __syncthreads();
    {
        int r = tid >> 2, seg = tid & 3;
        const uint4* s = (const uint4*)(os + r * 264 + seg * 64);
        uint4* d = (uint4*)(o + ((size_t)b * 4096 + n0 + r) * 256 + seg * 64);
#pragma unroll
        for (int i = 0; i < 8; i++) d[i] = s[i];
    }
}

__global__ void k_ln_res(const bf16* __restrict__ po, const float* __restrict__ x,
                         const float* __restrict__ xh, const float* __restrict__ xw,
                         const float* __restrict__ n2w, const float* __restrict__ n2b,
                         bf16* __restrict__ tn2) {
    __shared__ float t1s[16][256];
    int tid = threadIdx.x, c = tid;
    size_t row0 = (size_t)blockIdx.x * 16;
    int b = (int)(row0 >> 12);
    int n0 = (int)(row0 & 4095);
    int hh = n0 >> 6, w0 = n0 & 63;
    float hg = xh[((size_t)b * 256 + c) * 64 + hh];
    const float* xp = x + (((size_t)b * 256 + c) * 64 + hh) * 64 + w0;
    const float* wp = xw + ((size_t)b * 256 + c) * 64 + w0;
    for (int r = 0; r < 16; r++)
        t1s[r][c] = b2f(po[(row0 + r) * 256 + c]) + xp[r] * hg * wp[r];
    __syncthreads();
    int wv = tid >> 6, lane = tid & 63;
    float nw[4], nb[4];
#pragma unroll
    for (int k2 = 0; k2 < 4; k2++) { nw[k2] = n2w[lane + k2 * 64]; nb[k2] = n2b[lane + k2 * 64]; }
    for (int rr = 0; rr < 4; rr++) {
        int r = wv * 4 + rr;
        float s = 0.f, s2 = 0.f;
#pragma unroll
        for (int k2 = 0; k2 < 4; k2++) { float v = t1s[r][lane + k2 * 64]; s += v; s2 += v * v; }
#pragma unroll
        for (int off2 = 32; off2; off2 >>= 1) { s += __shfl_down(s, off2); s2 += __shfl_down(s2, off2); }
        s = __shfl(s, 0); s2 = __shfl(s2, 0);
        float m = s * (1.f / 256.f), var = s2 * (1.f / 256.f) - m * m;
        float inv = rsqrtf(fmaxf(var, 0.f) + 1e-6f);
#pragma unroll
        for (int k2 = 0; k2 < 4; k2++) {
            int cc = lane + k2 * 64;
            float v = t1s[r][cc];
            tn2[(row0 + r) * 256 + cc] = f2b((v - m) * inv * nw[k2] + nb[k2]);
        }
    }
}

__global__ void k_ln512(bf16* __restrict__ x2, const float* __restrict__ gnw,
                        const float* __restrict__ gnb) {
    __shared__ float s[16][512];
    int tid = threadIdx.x;
    size_t row0 = (size_t)blockIdx.x * 16;
    for (int i = tid; i < 16 * 512; i += 256) s[i >> 9][i & 511] = b2f(x2[row0 * 512 + i]);
    __syncthreads();
    int wv = tid >> 6, lane = tid & 63;
    float nw[8], nb[8];
#pragma unroll
    for (int k2 = 0; k2 < 8; k2++) { nw[k2] = gnw[lane + k2 * 64]; nb[k2] = gnb[lane + k2 * 64]; }
    for (int rr = 0; rr < 4; rr++) {
        int r = wv * 4 + rr;
        float a = 0.f, a2 = 0.f;
#pragma unroll
        for (int k2 = 0; k2 < 8; k2++) { float v = s[r][lane + k2 * 64]; a += v; a2 += v * v; }
#pragma unroll
        for (int off2 = 32; off2; off2 >>= 1) { a += __shfl_down(a, off2); a2 += __shfl_down(a2, off2); }
        a = __shfl(a, 0); a2 = __shfl(a2, 0);
        float m = a * (1.f / 512.f), var = a2 * (1.f / 512.f) - m * m;
        float inv = rsqrtf(fmaxf(var, 0.f) + 1e-5f);
#pragma unroll
        for (int k2 = 0; k2 < 8; k2++) {
            int e = lane + k2 * 64;
            float v = (s[r][e] - m) * inv * nw[k2] + nb[k2];
            x2[(row0 + r) * 512 + e] = f2b(v);
        }
    }
}

__global__ void k_gatec(const bf16* __restrict__ x2n, const float* __restrict__ gw,
                        const float* __restrict__ gb, bf16* __restrict__ x1io) {
    size_t idx = (size_t)blockIdx.x * 256 + threadIdx.x;
    int c = (int)(idx & 511);
    size_t bn = idx >> 9;
    int n = (int)(bn & 4095);
    size_t b = bn >> 12;
    int y = n >> 6, x = n & 63;
    float acc = gb[c];
    const float* w = gw + c * 9;
#pragma unroll
    for (int dy = -1; dy <= 1; dy++)
#pragma unroll
        for (int dx = -1; dx <= 1; dx++) {
            int yy = y + dy, xx = x + dx;
            if (yy >= 0 && yy < 64 && xx >= 0 && xx < 64)
                acc += b2f(x2n[(b * Nn + yy * 64 + xx) * 512 + c]) * w[(dy + 1) * 3 + (dx + 1)];
        }
    float g = b2f(x1io[idx]) * acc;
    x1io[idx] = f2b(g);
}

extern "C" void kernel_launch(void* const* d_in, const int* in_sizes, int n_in,
                              void* d_out, int out_size, void* d_ws, size_t ws_size,
                              hipStream_t stream) {
    const float* x = (const float*)d_in[0];
    const float* sda_conv_w = (const float*)d_in[1];
    const float* sda_gn_w = (const float*)d_in[2];
    const float* sda_gn_b = (const float*)d_in[3];
    const float* norm1_w = (const float*)d_in[4];
    const float* norm1_b = (const float*)d_in[5];
    const float* red_w = (const float*)d_in[6];
    const float* red_b = (const float*)d_in[7];
    const float* dw_w = (const float*)d_in[8];
    const float* dw_b = (const float*)d_in[9];
    const float* conv_w = (const float*)d_in[10];
    const float* conv_b = (const float*)d_in[11];
    const float* na_w = (const float*)d_in[12];
    const float* na_b = (const float*)d_in[13];
    const float* q_w = (const float*)d_in[14];
    const float* k_w = (const float*)d_in[15];
    const float* v_w = (const float*)d_in[16];
    const float* cpe_w = (const float*)d_in[17];
    const float* cpe_b = (const float*)d_in[18];
    const float* proj_w = (const float*)d_in[19];
    const float* proj_b = (const float*)d_in[20];
    const float* norm2_w = (const float*)d_in[21];
    const float* norm2_b = (const float*)d_in[22];
    const float* fc1_w = (const float*)d_in[23];
    const float* fc1_b = (const float*)d_in[24];
    const float* gnorm_w = (const float*)d_in[25];
    const float* gnorm_b = (const float*)d_in[26];
    const float* gconv_w = (const float*)d_in[27];
    const float* gconv_b = (const float*)d_in[28];
    const float* fc2_w = (const float*)d_in[29];
    const float* fc2_b = (const float*)d_in[30];
    float* outp = (float*)d_out;

    char* ws = (char*)d_ws;
    size_t off = 0;
    auto alloc = [&](size_t bytes) -> char* {
        char* p = ws + off;
        off += (bytes + 255) & ~(size_t)255;
        return p;
    };
    bf16* po = (bf16*)alloc((size_t)Mtot * Cn * 2);
    char* arena2 = alloc((size_t)Mtot * HALFn * 2);
    char* arena3 = alloc((size_t)Mtot * HALFn * 2);
    float* xmH = (float*)alloc((size_t)Bn * Cn * 64 * 4);
    float* xmW = (float*)alloc((size_t)Bn * Cn * 64 * 4);
    float* xh = (float*)alloc((size_t)Bn * Cn * 64 * 4);
    float* xw = (float*)alloc((size_t)Bn * Cn * 64 * 4);
    float* red2 = (float*)alloc((size_t)Bn * Cn * 16 * 4);
    float* dwr = (float*)alloc((size_t)Bn * Cn * 16 * 4);
    float* xr = (float*)alloc((size_t)Bn * 16 * 128 * 4);
    float* kb = (float*)alloc((size_t)Bn * 16 * 128 * 4);
    float* v0 = (float*)alloc((size_t)Bn * 16 * 256 * 4);
    float* vb = (float*)alloc((size_t)Bn * 16 * 256 * 4);
    bf16* qwT = (bf16*)alloc((size_t)128 * 256 * 2);
    bf16* pwT = (bf16*)alloc((size_t)256 * 256 * 2);
    bf16* f1T = (bf16*)alloc((size_t)1024 * 256 * 2);
    bf16* f2T = (bf16*)alloc((size_t)256 * 512 * 2);

    bf16* tn = (bf16*)d_out;
    bf16* qb = (bf16*)arena2;
    bf16* x1 = (bf16*)arena2;
    float* red1 = (float*)arena3;
    bf16* x2b = (bf16*)arena3;

    k_cvtw<<<(256 / 32) * (128 / 32), 256, 0, stream>>>(q_w, qwT, 256, 128);
    k_cvtw<<<(256 / 32) * (256 / 32), 256, 0, stream>>>(proj_w, pwT, 256, 256);
    k_cvtw<<<(256 / 32) * (1024 / 32), 256, 0, stream>>>(fc1_w, f1T, 256, 1024);
    k_cvtw<<<(512 / 32) * (256 / 32), 256, 0, stream>>>(fc2_w, f2T, 512, 256);

    k_pool<<<Bn * Cn, 256, 0, stream>>>(x, xmH, xmW);
    k_sda<<<Bn * 16, 256, 0, stream>>>(xmH, xmW, sda_conv_w, sda_gn_w, sda_gn_b, xh, xw);
    k_gate_norm1<<<Bn * 64, 256, 0, stream>>>(x, xh, xw, norm1_w, norm1_b, tn);
    k_red1<<<Bn * 16 * 4, 256, 0, stream>>>(tn, red_w, red_b, red1);
    k_red2<<<256, 256, 0, stream>>>(red1, red_w, red_b, red2);
    k_dw3<<<256, 256, 0, stream>>>(red2, dw_w, dw_b, dwr);
    k_conv1x1_ln<<<Bn * 16, 128, 0, stream>>>(dwr, conv_w, conv_b, na_w, na_b, xr);
    k_kv<<<Bn * 16, 256, 0, stream>>>(xr, k_w, v_w, kb, v0);
    k_cpe<<<256, 256, 0, stream>>>(v0, cpe_w, cpe_b, vb);
    gemm_q<<<(Mtot / 64) * 2, 256, 0, stream>>>(tn, qwT, qb);
    k_attn<<<Bn * 64, 256, 0, stream>>>(qb, kb, vb, tn);
    gemm_proj<<<(Mtot / 64) * 4, 256, 0, stream>>>(tn, pwT, proj_b, po);
    k_ln_res<<<Mtot / 16, 256, 0, stream>>>(po, x, xh, xw, norm2_w, norm2_b, tn);
    gemm_fc1<<<(Mtot / 64) * 16, 256, 0, stream>>>(tn, f1T, fc1_b, x1, x2b);
    k_ln512<<<Mtot / 16, 256, 0, stream>>>(x2b, gnorm_w, gnorm_b);
    k_gatec<<<(Mtot * HALFn) / 256, 256, 0, stream>>>(x2b, gconv_w, gconv_b, x1);
    gemm_fc2<<<(Mtot / 64) * 4, 256, 0, stream>>>(x1, f2T, fc2_b, po, x, xh, xw, outp);
}

// Round 7
// 1203.926 us; speedup vs baseline: 1.9309x; 1.1231x over previous
//
#include <hip/hip_runtime.h>
#include <hip/hip_bf16.h>
#include <cmath>

#define DEV __device__ __forceinline__

constexpr int Bn = 16, Cn = 256, Nn = 4096;
constexpr int NHn = 8, CRn = 128, HALFn = 512;
constexpr int Mtot = Bn * Nn;  // 65536 token rows

typedef __hip_bfloat16 bf16;
typedef __attribute__((ext_vector_type(8))) short bf16x8;
typedef __attribute__((ext_vector_type(4))) float f32x4;

DEV float b2f(bf16 v) { return __bfloat162float(v); }
DEV bf16 f2b(float v) { return __float2bfloat16(v); }
DEV float gelu_f(float x) { return 0.5f * x * (1.0f + erff(x * 0.70710678118654752f)); }

template <int NT>
DEV float2 block_sum2(float a, float b) {
    __shared__ float sh[2 * NT / 64];
    __syncthreads();
    int lane = threadIdx.x & 63, wv = threadIdx.x >> 6;
#pragma unroll
    for (int off = 32; off; off >>= 1) { a += __shfl_down(a, off); b += __shfl_down(b, off); }
    if (lane == 0) { sh[wv * 2] = a; sh[wv * 2 + 1] = b; }
    __syncthreads();
    float ta = 0.f, tb = 0.f;
#pragma unroll
    for (int i = 0; i < NT / 64; i++) { ta += sh[i * 2]; tb += sh[i * 2 + 1]; }
    return make_float2(ta, tb);
}

// ================= MFMA GEMM machinery =================
constexpr int LDP = 136;

DEV void stage64(const bf16* __restrict__ g, int stride, short* lds) {
    int t = threadIdx.x;
    int r = t >> 2, seg = t & 3;
    const uint4* src = (const uint4*)(g + (size_t)r * stride + seg * 32);
    uint4* dst = (uint4*)(lds + r * LDP + seg * 32);
#pragma unroll
    for (int i = 0; i < 4; i++) dst[i] = src[i];
}

DEV void compute_chunk(const short* lA, const short* lW, f32x4* acc) {
    int lane = threadIdx.x & 63;
    int w = threadIdx.x >> 6;
    const short* pa = lA + (w * 16 + (lane & 15)) * LDP + (lane >> 4) * 8;
    const short* pb = lW + (lane & 15) * LDP + (lane >> 4) * 8;
#pragma unroll
    for (int kt = 0; kt < 4; kt++) {
        bf16x8 a = *(const bf16x8*)(pa + kt * 32);
#pragma unroll
        for (int nt = 0; nt < 4; nt++) {
            bf16x8 b = *(const bf16x8*)(pb + nt * 16 * LDP + kt * 32);
            acc[nt] = __builtin_amdgcn_mfma_f32_16x16x32_bf16(a, b, acc[nt], 0, 0, 0);
        }
    }
}

template <int K>
DEV void gemm_main(const bf16* __restrict__ A, const bf16* __restrict__ Wt,
                   int mblk, int nblk, short* lA, short* lW, f32x4* acc) {
#pragma unroll
    for (int nt = 0; nt < 4; nt++)
#pragma unroll
        for (int i = 0; i < 4; i++) acc[nt][i] = 0.f;
    for (int kc = 0; kc < K / 128; kc++) {
        if (kc) __syncthreads();
        stage64(A + (size_t)mblk * 64 * K + kc * 128, K, lA);
        stage64(Wt + (size_t)nblk * 64 * K + kc * 128, K, lW);
        __syncthreads();
        compute_chunk(lA, lW, acc);
    }
}

__global__ void k_cvtw(const float* __restrict__ W, bf16* __restrict__ Wt, int K, int N) {
    __shared__ float t[32][33];
    int ntn = N >> 5;
    int bx = blockIdx.x % ntn, by = blockIdx.x / ntn;
    int tx = threadIdx.x & 31, ty = threadIdx.x >> 5;
#pragma unroll
    for (int i = 0; i < 4; i++)
        t[ty + i * 8][tx] = W[(size_t)(by * 32 + ty + i * 8) * N + bx * 32 + tx];
    __syncthreads();
#pragma unroll
    for (int i = 0; i < 4; i++)
        Wt[(size_t)(bx * 32 + ty + i * 8) * K + by * 32 + tx] = f2b(t[tx][ty + i * 8]);
}

__global__ void gemm_q(const bf16* __restrict__ A, const bf16* __restrict__ Wt,
                       bf16* __restrict__ out) {
    __shared__ short lA[64 * LDP], lW[64 * LDP];
    int mblk = blockIdx.x >> 1, nblk = blockIdx.x & 1;
    f32x4 acc[4];
    gemm_main<256>(A, Wt, mblk, nblk, lA, lW, acc);
    int lane = threadIdx.x & 63, w = threadIdx.x >> 6, m16 = lane & 15, quad = lane >> 4;
    size_t rowb = (size_t)mblk * 64 + w * 16 + quad * 4;
#pragma unroll
    for (int nt = 0; nt < 4; nt++) {
        int col = nblk * 64 + nt * 16 + m16;
#pragma unroll
        for (int reg = 0; reg < 4; reg++) out[(rowb + reg) * 128 + col] = f2b(acc[nt][reg]);
    }
}

__global__ void gemm_proj(const bf16* __restrict__ A, const bf16* __restrict__ Wt,
                          const float* __restrict__ pb, bf16* __restrict__ out) {
    __shared__ short lA[64 * LDP], lW[64 * LDP];
    int mblk = blockIdx.x >> 2, nblk = blockIdx.x & 3;
    f32x4 acc[4];
    gemm_main<256>(A, Wt, mblk, nblk, lA, lW, acc);
    int lane = threadIdx.x & 63, w = threadIdx.x >> 6, m16 = lane & 15, quad = lane >> 4;
    size_t rowb = (size_t)mblk * 64 + w * 16 + quad * 4;
#pragma unroll
    for (int nt = 0; nt < 4; nt++) {
        int col = nblk * 64 + nt * 16 + m16;
        float bv = pb[col];
#pragma unroll
        for (int reg = 0; reg < 4; reg++) out[(rowb + reg) * 256 + col] = f2b(acc[nt][reg] + bv);
    }
}

__global__ void gemm_fc1(const bf16* __restrict__ A, const bf16* __restrict__ Wt,
                         const float* __restrict__ fb, bf16* __restrict__ x1,
                         bf16* __restrict__ x2b) {
    __shared__ short lA[64 * LDP], lW[64 * LDP];
    int mblk = blockIdx.x >> 4, nblk = blockIdx.x & 15;
    f32x4 acc[4];
    gemm_main<256>(A, Wt, mblk, nblk, lA, lW, acc);
    int tid = threadIdx.x;
    int lane = tid & 63, w = tid >> 6, m16 = lane & 15, quad = lane >> 4;
    __syncthreads();
    bf16* ldsO = (bf16*)lA;
    int rl0 = w * 16 + quad * 4;
#pragma unroll
    for (int nt = 0; nt < 4; nt++) {
        int col = nblk * 64 + nt * 16 + m16;
        float bv = fb[col];
#pragma unroll
        for (int reg = 0; reg < 4; reg++)
            ldsO[(rl0 + reg) * 72 + nt * 16 + m16] = f2b(gelu_f(acc[nt][reg] + bv));
    }
    __syncthreads();
    int lm = tid >> 2, seg = tid & 3;
    int colg = nblk * 64 + seg * 16;
    bf16* dst = (colg < 512) ? (x1 + (size_t)(mblk * 64 + lm) * 512 + colg)
                             : (x2b + (size_t)(mblk * 64 + lm) * 512 + colg - 512);
    const uint4* s = (const uint4*)(ldsO + lm * 72 + seg * 16);
    uint4* d = (uint4*)dst;
    d[0] = s[0];
    d[1] = s[1];
}

__global__ void gemm_fc2(const bf16* __restrict__ A, const bf16* __restrict__ Wt,
                         const float* __restrict__ fb, const bf16* __restrict__ po,
                         const float* __restrict__ x, const float* __restrict__ xh,
                         const float* __restrict__ xw, float* __restrict__ outp) {
    __shared__ short lA[64 * LDP], lW[64 * LDP];
    int mblk = blockIdx.x >> 2, nblk = blockIdx.x & 3;
    f32x4 acc[4];
    gemm_main<512>(A, Wt, mblk, nblk, lA, lW, acc);
    int tid = threadIdx.x;
    int lane = tid & 63, w = tid >> 6, m16 = lane & 15, quad = lane >> 4;
    __syncthreads();
    float* ldsF = (float*)lA;
    int b = mblk >> 6;
    int hh = mblk & 63;
    int n0 = hh * 64;
    int rl0 = w * 16 + quad * 4;
#pragma unroll
    for (int nt = 0; nt < 4; nt++) {
        int c = nblk * 64 + nt * 16 + m16;
        float bv = fb[c];
        float hg = xh[((size_t)b * 256 + c) * 64 + hh];
        const float* xp = x + (((size_t)b * 256 + c) * 64 + hh) * 64 + rl0;
        const float* wp = xw + ((size_t)b * 256 + c) * 64 + rl0;
        const bf16* pp = po + ((size_t)mblk * 64 + rl0) * 256 + c;
#pragma unroll
        for (int reg = 0; reg < 4; reg++) {
            float v = acc[nt][reg] + bv + b2f(pp[reg * 256]) + xp[reg] * hg * wp[reg];
            ldsF[(rl0 + reg) * 65 + nt * 16 + m16] = v;
        }
    }
    __syncthreads();
    int cl = tid >> 2, ms = tid & 3;
    size_t ob = ((size_t)b * 256 + nblk * 64 + cl) * 4096 + n0 + ms * 16;
#pragma unroll
    for (int g2 = 0; g2 < 4; g2++) {
        float4 v4 = make_float4(ldsF[(ms * 16 + g2 * 4 + 0) * 65 + cl],
                                ldsF[(ms * 16 + g2 * 4 + 1) * 65 + cl],
                                ldsF[(ms * 16 + g2 * 4 + 2) * 65 + cl],
                                ldsF[(ms * 16 + g2 * 4 + 3) * 65 + cl]);
        *(float4*)(outp + ob + g2 * 4) = v4;
    }
}

// ================= non-GEMM kernels =================

__global__ void k_pool(const float* __restrict__ x, float* __restrict__ xmH, float* __restrict__ xmW) {
    __shared__ float t[4096];
    int blk = blockIdx.x;
    const float* xp = x + (size_t)blk * 4096;
    int tid = threadIdx.x;
    for (int k = 0; k < 16; k++) t[tid + k * 256] = xp[tid + k * 256];
    __syncthreads();
    if (tid < 64) {
        float rs = 0.f, cs = 0.f;
        for (int w = 0; w < 64; w++) {
            int ws = (w + tid) & 63;
            rs += t[tid * 64 + ws];
            cs += t[w * 64 + tid];
        }
        xmH[(size_t)blk * 64 + tid] = rs * (1.f / 64.f);
        xmW[(size_t)blk * 64 + tid] = cs * (1.f / 64.f);
    }
}

__global__ void k_sda(const float* __restrict__ xmH, const float* __restrict__ xmW,
                      const float* __restrict__ w7, const float* __restrict__ gnw,
                      const float* __restrict__ gnb, float* __restrict__ xh, float* __restrict__ xw) {
    int b = blockIdx.x >> 4, grp = blockIdx.x & 15;
    int c0 = grp * 16;
    int tid = threadIdx.x;
    __shared__ float y[2][1024];
    for (int p = 0; p < 2; p++) {
        const float* xm = (p == 0 ? xmH : xmW) + ((size_t)b * Cn + c0) * 64;
        for (int e = tid; e < 1024; e += 256) {
            int ci = e >> 6, i = e & 63;
            float acc = 0.f;
            const float* wc = w7 + (c0 + ci) * 7;
#pragma unroll
            for (int j = 0; j < 7; j++) {
                int ii = i + j - 3;
                if (ii >= 0 && ii < 64) acc += xm[ci * 64 + ii] * wc[j];
            }
            y[p][e] = acc;
        }
    }
    __syncthreads();
    for (int p = 0; p < 2; p++) {
        float s = 0.f, s2 = 0.f;
        for (int e = tid; e < 1024; e += 256) { float v = y[p][e]; s += v; s2 += v * v; }
        float2 r = block_sum2<256>(s, s2);
        float m = r.x * (1.f / 1024.f);
        float var = r.y * (1.f / 1024.f) - m * m;
        float inv = rsqrtf(fmaxf(var, 0.f) + 1e-5f);
        float* outp = (p == 0 ? xh : xw) + ((size_t)b * Cn + c0) * 64;
        for (int e = tid; e < 1024; e += 256) {
            int ci = e >> 6, i = e & 63;
            float v = (y[p][e] - m) * inv * gnw[c0 + ci] + gnb[c0 + ci];
            outp[ci * 64 + i] = v > 0.f ? v : 0.f;
        }
    }
}

__global__ void k_gate_norm1(const float* __restrict__ x, const float* __restrict__ xh,
                             const float* __restrict__ xw, const float* __restrict__ n1w,
                             const float* __restrict__ n1b, bf16* __restrict__ tn) {
    __shared__ float xs[256][65];
    __shared__ float ps[64][4], pq[64][4];
    int b = blockIdx.x >> 6, hh = blockIdx.x & 63;
    int c = threadIdx.x;
    float hx = xh[((size_t)b * 256 + c) * 64 + hh];
    const float* xrow = x + (((size_t)b * 256 + c) * 64 + hh) * 64;
    const float* wrow = xw + ((size_t)b * 256 + c) * 64;
#pragma unroll
    for (int w = 0; w < 64; w += 4) {
        float4 xv = *(const float4*)(xrow + w);
        float4 wv = *(const float4*)(wrow + w);
        xs[c][w + 0] = xv.x * hx * wv.x;
        xs[c][w + 1] = xv.y * hx * wv.y;
        xs[c][w + 2] = xv.z * hx * wv.z;
        xs[c][w + 3] = xv.w * hx * wv.w;
    }
    __syncthreads();
    int p = c >> 6, ww = c & 63;
    float s = 0.f, s2 = 0.f;
    for (int i = 0; i < 64; i++) { float v = xs[p * 64 + i][ww]; s += v; s2 += v * v; }
    ps[ww][p] = s;
    pq[ww][p] = s2;
    __syncthreads();
    float st = 0.f, qt = 0.f;
#pragma unroll
    for (int k = 0; k < 4; k++) { st += ps[ww][k]; qt += pq[ww][k]; }
    float m = st * (1.f / 256.f), var = qt * (1.f / 256.f) - m * m;
    float inv = rsqrtf(fmaxf(var, 0.f) + 1e-6f);
    size_t orow = ((size_t)b * 4096 + hh * 64 + ww) * 256 + p * 64;
    for (int j = 0; j < 64; j += 8) {
        uint4 u;
        short* ts = (short*)&u;
#pragma unroll
        for (int jj = 0; jj < 8; jj++) {
            int cc = p * 64 + j + jj;
            float v = (xs[cc][ww] - m) * inv * n1w[cc] + n1b[cc];
            bf16 h = f2b(v);
            ts[jj] = *(short*)&h;
        }
        *(uint4*)(tn + orow + j) = u;
    }
}

__global__ void k_red1(const bf16* __restrict__ tn, const float* __restrict__ rw,
                       const float* __restrict__ rb, float* __restrict__ red1) {
    int blk = blockIdx.x;
    int b = blk >> 6, yo = (blk >> 2) & 15, wq = blk & 3;
    int c = threadIdx.x;
    float wreg[16];
#pragma unroll
    for (int j = 0; j < 16; j++) wreg[j] = rw[c * 16 + j];
    float acc[4];
#pragma unroll
    for (int j = 0; j < 4; j++) acc[j] = rb[c];
    for (int dy = 0; dy < 4; dy++) {
        int hh = yo * 4 + dy;
        const bf16* row = tn + ((size_t)b * 4096 + hh * 64 + wq * 16) * 256 + c;
#pragma unroll
        for (int wl = 0; wl < 16; wl++) {
            float v = b2f(row[wl * 256]);
            acc[wl >> 2] += v * wreg[dy * 4 + (wl & 3)];
        }
    }
    float* dst = red1 + ((size_t)b * 256 + c) * 256 + yo * 16 + wq * 4;
    *(float4*)dst = make_float4(acc[0], acc[1], acc[2], acc[3]);
}

__global__ void k_red2(const float* __restrict__ red1, const float* __restrict__ rw,
                       const float* __restrict__ rb, float* __restrict__ red2) {
    int idx = blockIdx.x * 256 + threadIdx.x;
    int t = idx & 15, bc = idx >> 4;
    int c = bc & 255;
    int yo = t >> 2, xo = t & 3;
    float acc = rb[c];
    const float* w = rw + c * 16;
    const float* base = red1 + (size_t)bc * 256;
#pragma unroll
    for (int dy = 0; dy < 4; dy++)
#pragma unroll
        for (int dx = 0; dx < 4; dx++)
            acc += base[(yo * 4 + dy) * 16 + xo * 4 + dx] * w[dy * 4 + dx];
    red2[idx] = acc;
}

__global__ void k_dw3(const float* __restrict__ in, const float* __restrict__ w9,
                      const float* __restrict__ bb, float* __restrict__ outp) {
    int idx = blockIdx.x * 256 + threadIdx.x;
    int t = idx & 15, bc = idx >> 4, c = bc & 255;
    int y = t >> 2, x = t & 3;
    float acc = bb[c];
    const float* w = w9 + c * 9;
    const float* base = in + (size_t)bc * 16;
#pragma unroll
    for (int dy = -1; dy <= 1; dy++)
#pragma unroll
        for (int dx = -1; dx <= 1; dx++) {
            int yy = y + dy, xx = x + dx;
            if (yy >= 0 && yy < 4 && xx >= 0 && xx < 4)
                acc += base[yy * 4 + xx] * w[(dy + 1) * 3 + (dx + 1)];
        }
    outp[idx] = acc;
}

__global__ void k_conv1x1_ln(const float* __restrict__ dwr, const float* __restrict__ cw,
                             const float* __restrict__ cb, const float* __restrict__ naw,
                             const float* __restrict__ nab, float* __restrict__ xr) {
    int b = blockIdx.x >> 4, m = blockIdx.x & 15;
    int tid = threadIdx.x;
    __shared__ float in[256];
    for (int c = tid; c < 256; c += 128) in[c] = dwr[((size_t)b * Cn + c) * 16 + m];
    __syncthreads();
    float acc = cb[tid];
    const float* w = cw + tid * 256;
    for (int c = 0; c < 256; c++) acc += in[c] * w[c];
    float2 r = block_sum2<128>(acc, acc * acc);
    float mm = r.x * (1.f / 128.f), var = r.y * (1.f / 128.f) - mm * mm;
    float inv = rsqrtf(fmaxf(var, 0.f) + 1e-5f);
    float z = (acc - mm) * inv * naw[tid] + nab[tid];
    xr[(size_t)blockIdx.x * 128 + tid] = gelu_f(z);
}

__global__ void k_kv(const float* __restrict__ xr, const float* __restrict__ kw,
                     const float* __restrict__ vw, float* __restrict__ kbuf, float* __restrict__ v0) {
    int bm = blockIdx.x;
    int tid = threadIdx.x;
    __shared__ float in[128];
    if (tid < 128) in[tid] = xr[(size_t)bm * 128 + tid];
    __syncthreads();
    float acc = 0.f;
    for (int i = 0; i < 128; i++) acc += in[i] * vw[i * 256 + tid];
    v0[(size_t)bm * 256 + tid] = acc;
    if (tid < 128) {
        float ak = 0.f;
        for (int i = 0; i < 128; i++) ak += in[i] * kw[i * 128 + tid];
        kbuf[(size_t)bm * 128 + tid] = ak;
    }
}

__global__ void k_cpe(const float* __restrict__ v0, const float* __restrict__ cw,
                      const float* __restrict__ cb, float* __restrict__ v) {
    int idx = blockIdx.x * 256 + threadIdx.x;
    int c = idx & 255, bm = idx >> 8;
    int b = bm >> 4, m = bm & 15;
    int y = m >> 2, x = m & 3;
    float acc = v0[idx] + cb[c];
#pragma unroll
    for (int dy = -1; dy <= 1; dy++)
#pragma unroll
        for (int dx = -1; dx <= 1; dx++) {
            int yy = y + dy, xx = x + dx;
            if (yy >= 0 && yy < 4 && xx >= 0 && xx < 4)
                acc += v0[((size_t)b * 16 + yy * 4 + xx) * 256 + c] * cw[c * 9 + (dy + 1) * 3 + (dx + 1)];
        }
    v[idx] = acc;
}

// ---- K10: block = (b, 64-row chunk), all heads; coalesced q/o.
// __launch_bounds__(256,2): keep qr[16]+sc[16]+ov[32] in VGPRs (spill fix —
// default heuristic allocated 64 VGPRs and spilled ~900 MB to scratch).
__global__ void __launch_bounds__(256, 2)
k_attn(const bf16* __restrict__ q, const float* __restrict__ kbuf,
       const float* __restrict__ v, bf16* o) {
    __shared__ float ks2[8 * 260];
    __shared__ float vs2[8 * 516];
    __shared__ short qs[64 * 136];
    __shared__ short os[64 * 264];
    int tid = threadIdx.x;
    int b = blockIdx.x >> 6, chunk = blockIdx.x & 63;
    int n0 = chunk * 64;
    const float* kbp = kbuf + (size_t)b * 2048;
    for (int i = tid; i < 2048; i += 256) {
        int m = i >> 7, rem = i & 127, h = rem >> 4, d = rem & 15;
        ks2[h * 260 + m * 16 + d] = kbp[i];
    }
    const float* vbp = v + (size_t)b * 4096;
    for (int i = tid; i < 4096; i += 256) {
        int m = i >> 8, rem = i & 255, h = rem >> 5, e = rem & 31;
        vs2[h * 516 + m * 32 + e] = vbp[i];
    }
    {
        int r = tid >> 2, seg = tid & 3;
        const uint4* src = (const uint4*)(q + ((size_t)b * 4096 + n0 + r) * 128 + seg * 32);
        uint4* dst = (uint4*)(qs + r * 136 + seg * 32);
#pragma unroll
        for (int i = 0; i < 4; i++) dst[i] = src[i];
    }
    __syncthreads();
#pragma unroll
    for (int it = 0; it < 2; it++) {
        int task = it * 256 + tid;
        int row = task >> 3, h = task & 7;
        const short* qp = qs + row * 136 + h * 16;
        float qr[16];
#pragma unroll
        for (int d = 0; d < 16; d++) qr[d] = b2f(*(const bf16*)(qp + d));
        const float* kh = ks2 + h * 260;
        float sc[16];
        float mx = -1e30f;
#pragma unroll
        for (int m = 0; m < 16; m++) {
            float s = 0.f;
#pragma unroll
            for (int d = 0; d < 16; d++) s += qr[d] * kh[m * 16 + d];
            s *= 0.25f;
            sc[m] = s;
            mx = fmaxf(mx, s);
        }
        float den = 0.f;
#pragma unroll
        for (int m = 0; m < 16; m++) { sc[m] = expf(sc[m] - mx); den += sc[m]; }
        float rden = 1.f / den;
        const float* vh = vs2 + h * 516;
        float ov[32];
#pragma unroll
        for (int e = 0; e < 32; e++) ov[e] = 0.f;
#pragma unroll
        for (int m = 0; m < 16; m++) {
            float p = sc[m] * rden;
#pragma unroll
            for (int e = 0; e < 32; e++) ov[e] += p * vh[m * 32 + e];
        }
        short* op = os + row * 264 + h * 32;
#pragma unroll
        for (int e = 0; e < 32; e++) {
            bf16 hv = f2b(ov[e]);
            op[e] = *(short*)&hv;
        }
    }
    __syncthreads();
    {
        int r = tid >> 2, seg = tid & 3;
        const uint4* s = (const uint4*)(os + r * 264 + seg * 64);
        uint4* d = (uint4*)(o + ((size_t)b * 4096 + n0 + r) * 256 + seg * 64);
#pragma unroll
        for (int i = 0; i < 8; i++) d[i] = s[i];
    }
}

__global__ void k_ln_res(const bf16* __restrict__ po, const float* __restrict__ x,
                         const float* __restrict__ xh, const float* __restrict__ xw,
                         const float* __restrict__ n2w, const float* __restrict__ n2b,
                         bf16* __restrict__ tn2) {
    __shared__ float t1s[16][256];
    int tid = threadIdx.x, c = tid;
    size_t row0 = (size_t)blockIdx.x * 16;
    int b = (int)(row0 >> 12);
    int n0 = (int)(row0 & 4095);
    int hh = n0 >> 6, w0 = n0 & 63;
    float hg = xh[((size_t)b * 256 + c) * 64 + hh];
    const float* xp = x + (((size_t)b * 256 + c) * 64 + hh) * 64 + w0;
    const float* wp = xw + ((size_t)b * 256 + c) * 64 + w0;
    for (int r = 0; r < 16; r++)
        t1s[r][c] = b2f(po[(row0 + r) * 256 + c]) + xp[r] * hg * wp[r];
    __syncthreads();
    int wv = tid >> 6, lane = tid & 63;
    float nw[4], nb[4];
#pragma unroll
    for (int k2 = 0; k2 < 4; k2++) { nw[k2] = n2w[lane + k2 * 64]; nb[k2] = n2b[lane + k2 * 64]; }
    for (int rr = 0; rr < 4; rr++) {
        int r = wv * 4 + rr;
        float s = 0.f, s2 = 0.f;
#pragma unroll
        for (int k2 = 0; k2 < 4; k2++) { float v = t1s[r][lane + k2 * 64]; s += v; s2 += v * v; }
#pragma unroll
        for (int off2 = 32; off2; off2 >>= 1) { s += __shfl_down(s, off2); s2 += __shfl_down(s2, off2); }
        s = __shfl(s, 0); s2 = __shfl(s2, 0);
        float m = s * (1.f / 256.f), var = s2 * (1.f / 256.f) - m * m;
        float inv = rsqrtf(fmaxf(var, 0.f) + 1e-6f);
#pragma unroll
        for (int k2 = 0; k2 < 4; k2++) {
            int cc = lane + k2 * 64;
            float v = t1s[r][cc];
            tn2[(row0 + r) * 256 + cc] = f2b((v - m) * inv * nw[k2] + nb[k2]);
        }
    }
}

__global__ void k_ln512(bf16* __restrict__ x2, const float* __restrict__ gnw,
                        const float* __restrict__ gnb) {
    __shared__ float s[16][512];
    int tid = threadIdx.x;
    size_t row0 = (size_t)blockIdx.x * 16;
    for (int i = tid; i < 16 * 512; i += 256) s[i >> 9][i & 511] = b2f(x2[row0 * 512 + i]);
    __syncthreads();
    int wv = tid >> 6, lane = tid & 63;
    float nw[8], nb[8];
#pragma unroll
    for (int k2 = 0; k2 < 8; k2++) { nw[k2] = gnw[lane + k2 * 64]; nb[k2] = gnb[lane + k2 * 64]; }
    for (int rr = 0; rr < 4; rr++) {
        int r = wv * 4 + rr;
        float a = 0.f, a2 = 0.f;
#pragma unroll
        for (int k2 = 0; k2 < 8; k2++) { float v = s[r][lane + k2 * 64]; a += v; a2 += v * v; }
#pragma unroll
        for (int off2 = 32; off2; off2 >>= 1) { a += __shfl_down(a, off2); a2 += __shfl_down(a2, off2); }
        a = __shfl(a, 0); a2 = __shfl(a2, 0);
        float m = a * (1.f / 512.f), var = a2 * (1.f / 512.f) - m * m;
        float inv = rsqrtf(fmaxf(var, 0.f) + 1e-5f);
#pragma unroll
        for (int k2 = 0; k2 < 8; k2++) {
            int e = lane + k2 * 64;
            float v = (s[r][e] - m) * inv * nw[k2] + nb[k2];
            x2[(row0 + r) * 512 + e] = f2b(v);
        }
    }
}

__global__ void k_gatec(const bf16* __restrict__ x2n, const float* __restrict__ gw,
                        const float* __restrict__ gb, bf16* __restrict__ x1io) {
    size_t idx = (size_t)blockIdx.x * 256 + threadIdx.x;
    int c = (int)(idx & 511);
    size_t bn = idx >> 9;
    int n = (int)(bn & 4095);
    size_t b = bn >> 12;
    int y = n >> 6, x = n & 63;
    float acc = gb[c];
    const float* w = gw + c * 9;
#pragma unroll
    for (int dy = -1; dy <= 1; dy++)
#pragma unroll
        for (int dx = -1; dx <= 1; dx++) {
            int yy = y + dy, xx = x + dx;
            if (yy >= 0 && yy < 64 && xx >= 0 && xx < 64)
                acc += b2f(x2n[(b * Nn + yy * 64 + xx) * 512 + c]) * w[(dy + 1) * 3 + (dx + 1)];
        }
    float g = b2f(x1io[idx]) * acc;
    x1io[idx] = f2b(g);
}

extern "C" void kernel_launch(void* const* d_in, const int* in_sizes, int n_in,
                              void* d_out, int out_size, void* d_ws, size_t ws_size,
                              hipStream_t stream) {
    const float* x = (const float*)d_in[0];
    const float* sda_conv_w = (const float*)d_in[1];
    const float* sda_gn_w = (const float*)d_in[2];
    const float* sda_gn_b = (const float*)d_in[3];
    const float* norm1_w = (const float*)d_in[4];
    const float* norm1_b = (const float*)d_in[5];
    const float* red_w = (const float*)d_in[6];
    const float* red_b = (const float*)d_in[7];
    const float* dw_w = (const float*)d_in[8];
    const float* dw_b = (const float*)d_in[9];
    const float* conv_w = (const float*)d_in[10];
    const float* conv_b = (const float*)d_in[11];
    const float* na_w = (const float*)d_in[12];
    const float* na_b = (const float*)d_in[13];
    const float* q_w = (const float*)d_in[14];
    const float* k_w = (const float*)d_in[15];
    const float* v_w = (const float*)d_in[16];
    const float* cpe_w = (const float*)d_in[17];
    const float* cpe_b = (const float*)d_in[18];
    const float* proj_w = (const float*)d_in[19];
    const float* proj_b = (const float*)d_in[20];
    const float* norm2_w = (const float*)d_in[21];
    const float* norm2_b = (const float*)d_in[22];
    const float* fc1_w = (const float*)d_in[23];
    const float* fc1_b = (const float*)d_in[24];
    const float* gnorm_w = (const float*)d_in[25];
    const float* gnorm_b = (const float*)d_in[26];
    const float* gconv_w = (const float*)d_in[27];
    const float* gconv_b = (const float*)d_in[28];
    const float* fc2_w = (const float*)d_in[29];
    const float* fc2_b = (const float*)d_in[30];
    float* outp = (float*)d_out;

    char* ws = (char*)d_ws;
    size_t off = 0;
    auto alloc = [&](size_t bytes) -> char* {
        char* p = ws + off;
        off += (bytes + 255) & ~(size_t)255;
        return p;
    };
    bf16* po = (bf16*)alloc((size_t)Mtot * Cn * 2);
    char* arena2 = alloc((size_t)Mtot * HALFn * 2);
    char* arena3 = alloc((size_t)Mtot * HALFn * 2);
    float* xmH = (float*)alloc((size_t)Bn * Cn * 64 * 4);
    float* xmW = (float*)alloc((size_t)Bn * Cn * 64 * 4);
    float* xh = (float*)alloc((size_t)Bn * Cn * 64 * 4);
    float* xw = (float*)alloc((size_t)Bn * Cn * 64 * 4);
    float* red2 = (float*)alloc((size_t)Bn * Cn * 16 * 4);
    float* dwr = (float*)alloc((size_t)Bn * Cn * 16 * 4);
    float* xr = (float*)alloc((size_t)Bn * 16 * 128 * 4);
    float* kb = (float*)alloc((size_t)Bn * 16 * 128 * 4);
    float* v0 = (float*)alloc((size_t)Bn * 16 * 256 * 4);
    float* vb = (float*)alloc((size_t)Bn * 16 * 256 * 4);
    bf16* qwT = (bf16*)alloc((size_t)128 * 256 * 2);
    bf16* pwT = (bf16*)alloc((size_t)256 * 256 * 2);
    bf16* f1T = (bf16*)alloc((size_t)1024 * 256 * 2);
    bf16* f2T = (bf16*)alloc((size_t)256 * 512 * 2);

    bf16* tn = (bf16*)d_out;
    bf16* qb = (bf16*)arena2;
    bf16* x1 = (bf16*)arena2;
    float* red1 = (float*)arena3;
    bf16* x2b = (bf16*)arena3;

    k_cvtw<<<(256 / 32) * (128 / 32), 256, 0, stream>>>(q_w, qwT, 256, 128);
    k_cvtw<<<(256 / 32) * (256 / 32), 256, 0, stream>>>(proj_w, pwT, 256, 256);
    k_cvtw<<<(256 / 32) * (1024 / 32), 256, 0, stream>>>(fc1_w, f1T, 256, 1024);
    k_cvtw<<<(512 / 32) * (256 / 32), 256, 0, stream>>>(fc2_w, f2T, 512, 256);

    k_pool<<<Bn * Cn, 256, 0, stream>>>(x, xmH, xmW);
    k_sda<<<Bn * 16, 256, 0, stream>>>(xmH, xmW, sda_conv_w, sda_gn_w, sda_gn_b, xh, xw);
    k_gate_norm1<<<Bn * 64, 256, 0, stream>>>(x, xh, xw, norm1_w, norm1_b, tn);
    k_red1<<<Bn * 16 * 4, 256, 0, stream>>>(tn, red_w, red_b, red1);
    k_red2<<<256, 256, 0, stream>>>(red1, red_w, red_b, red2);
    k_dw3<<<256, 256, 0, stream>>>(red2, dw_w, dw_b, dwr);
    k_conv1x1_ln<<<Bn * 16, 128, 0, stream>>>(dwr, conv_w, conv_b, na_w, na_b, xr);
    k_kv<<<Bn * 16, 256, 0, stream>>>(xr, k_w, v_w, kb, v0);
    k_cpe<<<256, 256, 0, stream>>>(v0, cpe_w, cpe_b, vb);
    gemm_q<<<(Mtot / 64) * 2, 256, 0, stream>>>(tn, qwT, qb);
    k_attn<<<Bn * 64, 256, 0, stream>>>(qb, kb, vb, tn);
    gemm_proj<<<(Mtot / 64) * 4, 256, 0, stream>>>(tn, pwT, proj_b, po);
    k_ln_res<<<Mtot / 16, 256, 0, stream>>>(po, x, xh, xw, norm2_w, norm2_b, tn);
    gemm_fc1<<<(Mtot / 64) * 16, 256, 0, stream>>>(tn, f1T, fc1_b, x1, x2b);
    k_ln512<<<Mtot / 16, 256, 0, stream>>>(x2b, gnorm_w, gnorm_b);
    k_gatec<<<(Mtot * HALFn) / 256, 256, 0, stream>>>(x2b, gconv_w, gconv_b, x1);
    gemm_fc2<<<(Mtot / 64) * 4, 256, 0, stream>>>(x1, f2T, fc2_b, po, x, xh, xw, outp);
}

// Round 9
// 852.857 us; speedup vs baseline: 2.7257x; 1.4116x over previous
//
#include <hip/hip_runtime.h>
#include <hip/hip_bf16.h>
#include <cmath>

#define DEV __device__ __forceinline__

constexpr int Bn = 16, Cn = 256, Nn = 4096;
constexpr int NHn = 8, CRn = 128, HALFn = 512;
constexpr int Mtot = Bn * Nn;  // 65536 token rows

typedef __hip_bfloat16 bf16;
typedef __attribute__((ext_vector_type(8))) short bf16x8;
typedef __attribute__((ext_vector_type(4))) float f32x4;

DEV float b2f(bf16 v) { return __bfloat162float(v); }
DEV bf16 f2b(float v) { return __float2bfloat16(v); }
DEV float gelu_f(float x) { return 0.5f * x * (1.0f + erff(x * 0.70710678118654752f)); }

template <int NT>
DEV float2 block_sum2(float a, float b) {
    __shared__ float sh[2 * NT / 64];
    __syncthreads();
    int lane = threadIdx.x & 63, wv = threadIdx.x >> 6;
#pragma unroll
    for (int off = 32; off; off >>= 1) { a += __shfl_down(a, off); b += __shfl_down(b, off); }
    if (lane == 0) { sh[wv * 2] = a; sh[wv * 2 + 1] = b; }
    __syncthreads();
    float ta = 0.f, tb = 0.f;
#pragma unroll
    for (int i = 0; i < NT / 64; i++) { ta += sh[i * 2]; tb += sh[i * 2 + 1]; }
    return make_float2(ta, tb);
}

// ================= MFMA GEMM machinery =================
constexpr int LDP = 136;

DEV void stage64(const bf16* __restrict__ g, int stride, short* lds) {
    int t = threadIdx.x;
    int r = t >> 2, seg = t & 3;
    const uint4* src = (const uint4*)(g + (size_t)r * stride + seg * 32);
    uint4* dst = (uint4*)(lds + r * LDP + seg * 32);
#pragma unroll
    for (int i = 0; i < 4; i++) dst[i] = src[i];
}

DEV void compute_chunk(const short* lA, const short* lW, f32x4* acc) {
    int lane = threadIdx.x & 63;
    int w = threadIdx.x >> 6;
    const short* pa = lA + (w * 16 + (lane & 15)) * LDP + (lane >> 4) * 8;
    const short* pb = lW + (lane & 15) * LDP + (lane >> 4) * 8;
#pragma unroll
    for (int kt = 0; kt < 4; kt++) {
        bf16x8 a = *(const bf16x8*)(pa + kt * 32);
#pragma unroll
        for (int nt = 0; nt < 4; nt++) {
            bf16x8 b = *(const bf16x8*)(pb + nt * 16 * LDP + kt * 32);
            acc[nt] = __builtin_amdgcn_mfma_f32_16x16x32_bf16(a, b, acc[nt], 0, 0, 0);
        }
    }
}

template <int K>
DEV void gemm_main(const bf16* __restrict__ A, const bf16* __restrict__ Wt,
                   int mblk, int nblk, short* lA, short* lW, f32x4* acc) {
#pragma unroll
    for (int nt = 0; nt < 4; nt++)
#pragma unroll
        for (int i = 0; i < 4; i++) acc[nt][i] = 0.f;
    for (int kc = 0; kc < K / 128; kc++) {
        if (kc) __syncthreads();
        stage64(A + (size_t)mblk * 64 * K + kc * 128, K, lA);
        stage64(Wt + (size_t)nblk * 64 * K + kc * 128, K, lW);
        __syncthreads();
        compute_chunk(lA, lW, acc);
    }
}

__global__ void k_cvtw(const float* __restrict__ W, bf16* __restrict__ Wt, int K, int N) {
    __shared__ float t[32][33];
    int ntn = N >> 5;
    int bx = blockIdx.x % ntn, by = blockIdx.x / ntn;
    int tx = threadIdx.x & 31, ty = threadIdx.x >> 5;
#pragma unroll
    for (int i = 0; i < 4; i++)
        t[ty + i * 8][tx] = W[(size_t)(by * 32 + ty + i * 8) * N + bx * 32 + tx];
    __syncthreads();
#pragma unroll
    for (int i = 0; i < 4; i++)
        Wt[(size_t)(bx * 32 + ty + i * 8) * K + by * 32 + tx] = f2b(t[tx][ty + i * 8]);
}

__global__ void gemm_q(const bf16* __restrict__ A, const bf16* __restrict__ Wt,
                       bf16* __restrict__ out) {
    __shared__ short lA[64 * LDP], lW[64 * LDP];
    int mblk = blockIdx.x >> 1, nblk = blockIdx.x & 1;
    f32x4 acc[4];
    gemm_main<256>(A, Wt, mblk, nblk, lA, lW, acc);
    int lane = threadIdx.x & 63, w = threadIdx.x >> 6, m16 = lane & 15, quad = lane >> 4;
    size_t rowb = (size_t)mblk * 64 + w * 16 + quad * 4;
#pragma unroll
    for (int nt = 0; nt < 4; nt++) {
        int col = nblk * 64 + nt * 16 + m16;
#pragma unroll
        for (int reg = 0; reg < 4; reg++) out[(rowb + reg) * 128 + col] = f2b(acc[nt][reg]);
    }
}

__global__ void gemm_proj(const bf16* __restrict__ A, const bf16* __restrict__ Wt,
                          const float* __restrict__ pb, bf16* __restrict__ out) {
    __shared__ short lA[64 * LDP], lW[64 * LDP];
    int mblk = blockIdx.x >> 2, nblk = blockIdx.x & 3;
    f32x4 acc[4];
    gemm_main<256>(A, Wt, mblk, nblk, lA, lW, acc);
    int lane = threadIdx.x & 63, w = threadIdx.x >> 6, m16 = lane & 15, quad = lane >> 4;
    size_t rowb = (size_t)mblk * 64 + w * 16 + quad * 4;
#pragma unroll
    for (int nt = 0; nt < 4; nt++) {
        int col = nblk * 64 + nt * 16 + m16;
        float bv = pb[col];
#pragma unroll
        for (int reg = 0; reg < 4; reg++) out[(rowb + reg) * 256 + col] = f2b(acc[nt][reg] + bv);
    }
}

__global__ void gemm_fc1(const bf16* __restrict__ A, const bf16* __restrict__ Wt,
                         const float* __restrict__ fb, bf16* __restrict__ x1,
                         bf16* __restrict__ x2b) {
    __shared__ short lA[64 * LDP], lW[64 * LDP];
    int mblk = blockIdx.x >> 4, nblk = blockIdx.x & 15;
    f32x4 acc[4];
    gemm_main<256>(A, Wt, mblk, nblk, lA, lW, acc);
    int tid = threadIdx.x;
    int lane = tid & 63, w = tid >> 6, m16 = lane & 15, quad = lane >> 4;
    __syncthreads();
    bf16* ldsO = (bf16*)lA;
    int rl0 = w * 16 + quad * 4;
#pragma unroll
    for (int nt = 0; nt < 4; nt++) {
        int col = nblk * 64 + nt * 16 + m16;
        float bv = fb[col];
#pragma unroll
        for (int reg = 0; reg < 4; reg++)
            ldsO[(rl0 + reg) * 72 + nt * 16 + m16] = f2b(gelu_f(acc[nt][reg] + bv));
    }
    __syncthreads();
    int lm = tid >> 2, seg = tid & 3;
    int colg = nblk * 64 + seg * 16;
    bf16* dst = (colg < 512) ? (x1 + (size_t)(mblk * 64 + lm) * 512 + colg)
                             : (x2b + (size_t)(mblk * 64 + lm) * 512 + colg - 512);
    const uint4* s = (const uint4*)(ldsO + lm * 72 + seg * 16);
    uint4* d = (uint4*)dst;
    d[0] = s[0];
    d[1] = s[1];
}

__global__ void gemm_fc2(const bf16* __restrict__ A, const bf16* __restrict__ Wt,
                         const float* __restrict__ fb, const bf16* __restrict__ po,
                         const float* __restrict__ x, const float* __restrict__ xh,
                         const float* __restrict__ xw, float* __restrict__ outp) {
    __shared__ short lA[64 * LDP], lW[64 * LDP];
    int mblk = blockIdx.x >> 2, nblk = blockIdx.x & 3;
    f32x4 acc[4];
    gemm_main<512>(A, Wt, mblk, nblk, lA, lW, acc);
    int tid = threadIdx.x;
    int lane = tid & 63, w = tid >> 6, m16 = lane & 15, quad = lane >> 4;
    __syncthreads();
    float* ldsF = (float*)lA;
    int b = mblk >> 6;
    int hh = mblk & 63;
    int n0 = hh * 64;
    int rl0 = w * 16 + quad * 4;
#pragma unroll
    for (int nt = 0; nt < 4; nt++) {
        int c = nblk * 64 + nt * 16 + m16;
        float bv = fb[c];
        float hg = xh[((size_t)b * 256 + c) * 64 + hh];
        const float* xp = x + (((size_t)b * 256 + c) * 64 + hh) * 64 + rl0;
        const float* wp = xw + ((size_t)b * 256 + c) * 64 + rl0;
        const bf16* pp = po + ((size_t)mblk * 64 + rl0) * 256 + c;
#pragma unroll
        for (int reg = 0; reg < 4; reg++) {
            float v = acc[nt][reg] + bv + b2f(pp[reg * 256]) + xp[reg] * hg * wp[reg];
            ldsF[(rl0 + reg) * 65 + nt * 16 + m16] = v;
        }
    }
    __syncthreads();
    int cl = tid >> 2, ms = tid & 3;
    size_t ob = ((size_t)b * 256 + nblk * 64 + cl) * 4096 + n0 + ms * 16;
#pragma unroll
    for (int g2 = 0; g2 < 4; g2++) {
        float4 v4 = make_float4(ldsF[(ms * 16 + g2 * 4 + 0) * 65 + cl],
                                ldsF[(ms * 16 + g2 * 4 + 1) * 65 + cl],
                                ldsF[(ms * 16 + g2 * 4 + 2) * 65 + cl],
                                ldsF[(ms * 16 + g2 * 4 + 3) * 65 + cl]);
        *(float4*)(outp + ob + g2 * 4) = v4;
    }
}

// ================= non-GEMM kernels =================

__global__ void k_pool(const float* __restrict__ x, float* __restrict__ xmH, float* __restrict__ xmW) {
    __shared__ float t[4096];
    int blk = blockIdx.x;
    const float* xp = x + (size_t)blk * 4096;
    int tid = threadIdx.x;
    for (int k = 0; k < 16; k++) t[tid + k * 256] = xp[tid + k * 256];
    __syncthreads();
    if (tid < 64) {
        float rs = 0.f, cs = 0.f;
        for (int w = 0; w < 64; w++) {
            int ws = (w + tid) & 63;
            rs += t[tid * 64 + ws];
            cs += t[w * 64 + tid];
        }
        xmH[(size_t)blk * 64 + tid] = rs * (1.f / 64.f);
        xmW[(size_t)blk * 64 + tid] = cs * (1.f / 64.f);
    }
}

__global__ void k_sda(const float* __restrict__ xmH, const float* __restrict__ xmW,
                      const float* __restrict__ w7, const float* __restrict__ gnw,
                      const float* __restrict__ gnb, float* __restrict__ xh, float* __restrict__ xw) {
    int b = blockIdx.x >> 4, grp = blockIdx.x & 15;
    int c0 = grp * 16;
    int tid = threadIdx.x;
    __shared__ float y[2][1024];
    for (int p = 0; p < 2; p++) {
        const float* xm = (p == 0 ? xmH : xmW) + ((size_t)b * Cn + c0) * 64;
        for (int e = tid; e < 1024; e += 256) {
            int ci = e >> 6, i = e & 63;
            float acc = 0.f;
            const float* wc = w7 + (c0 + ci) * 7;
#pragma unroll
            for (int j = 0; j < 7; j++) {
                int ii = i + j - 3;
                if (ii >= 0 && ii < 64) acc += xm[ci * 64 + ii] * wc[j];
            }
            y[p][e] = acc;
        }
    }
    __syncthreads();
    for (int p = 0; p < 2; p++) {
        float s = 0.f, s2 = 0.f;
        for (int e = tid; e < 1024; e += 256) { float v = y[p][e]; s += v; s2 += v * v; }
        float2 r = block_sum2<256>(s, s2);
        float m = r.x * (1.f / 1024.f);
        float var = r.y * (1.f / 1024.f) - m * m;
        float inv = rsqrtf(fmaxf(var, 0.f) + 1e-5f);
        float* outp = (p == 0 ? xh : xw) + ((size_t)b * Cn + c0) * 64;
        for (int e = tid; e < 1024; e += 256) {
            int ci = e >> 6, i = e & 63;
            float v = (y[p][e] - m) * inv * gnw[c0 + ci] + gnb[c0 + ci];
            outp[ci * 64 + i] = v > 0.f ? v : 0.f;
        }
    }
}

__global__ void k_gate_norm1(const float* __restrict__ x, const float* __restrict__ xh,
                             const float* __restrict__ xw, const float* __restrict__ n1w,
                             const float* __restrict__ n1b, bf16* __restrict__ tn) {
    __shared__ float xs[256][65];
    __shared__ float ps[64][4], pq[64][4];
    int b = blockIdx.x >> 6, hh = blockIdx.x & 63;
    int c = threadIdx.x;
    float hx = xh[((size_t)b * 256 + c) * 64 + hh];
    const float* xrow = x + (((size_t)b * 256 + c) * 64 + hh) * 64;
    const float* wrow = xw + ((size_t)b * 256 + c) * 64;
#pragma unroll
    for (int w = 0; w < 64; w += 4) {
        float4 xv = *(const float4*)(xrow + w);
        float4 wv = *(const float4*)(wrow + w);
        xs[c][w + 0] = xv.x * hx * wv.x;
        xs[c][w + 1] = xv.y * hx * wv.y;
        xs[c][w + 2] = xv.z * hx * wv.z;
        xs[c][w + 3] = xv.w * hx * wv.w;
    }
    __syncthreads();
    int p = c >> 6, ww = c & 63;
    float s = 0.f, s2 = 0.f;
    for (int i = 0; i < 64; i++) { float v = xs[p * 64 + i][ww]; s += v; s2 += v * v; }
    ps[ww][p] = s;
    pq[ww][p] = s2;
    __syncthreads();
    float st = 0.f, qt = 0.f;
#pragma unroll
    for (int k = 0; k < 4; k++) { st += ps[ww][k]; qt += pq[ww][k]; }
    float m = st * (1.f / 256.f), var = qt * (1.f / 256.f) - m * m;
    float inv = rsqrtf(fmaxf(var, 0.f) + 1e-6f);
    size_t orow = ((size_t)b * 4096 + hh * 64 + ww) * 256 + p * 64;
    for (int j = 0; j < 64; j += 8) {
        uint4 u;
        short* ts = (short*)&u;
#pragma unroll
        for (int jj = 0; jj < 8; jj++) {
            int cc = p * 64 + j + jj;
            float v = (xs[cc][ww] - m) * inv * n1w[cc] + n1b[cc];
            bf16 h = f2b(v);
            ts[jj] = *(short*)&h;
        }
        *(uint4*)(tn + orow + j) = u;
    }
}

__global__ void k_red1(const bf16* __restrict__ tn, const float* __restrict__ rw,
                       const float* __restrict__ rb, float* __restrict__ red1) {
    int blk = blockIdx.x;
    int b = blk >> 6, yo = (blk >> 2) & 15, wq = blk & 3;
    int c = threadIdx.x;
    float wreg[16];
#pragma unroll
    for (int j = 0; j < 16; j++) wreg[j] = rw[c * 16 + j];
    float acc[4];
#pragma unroll
    for (int j = 0; j < 4; j++) acc[j] = rb[c];
    for (int dy = 0; dy < 4; dy++) {
        int hh = yo * 4 + dy;
        const bf16* row = tn + ((size_t)b * 4096 + hh * 64 + wq * 16) * 256 + c;
#pragma unroll
        for (int wl = 0; wl < 16; wl++) {
            float v = b2f(row[wl * 256]);
            acc[wl >> 2] += v * wreg[dy * 4 + (wl & 3)];
        }
    }
    float* dst = red1 + ((size_t)b * 256 + c) * 256 + yo * 16 + wq * 4;
    *(float4*)dst = make_float4(acc[0], acc[1], acc[2], acc[3]);
}

__global__ void k_red2(const float* __restrict__ red1, const float* __restrict__ rw,
                       const float* __restrict__ rb, float* __restrict__ red2) {
    int idx = blockIdx.x * 256 + threadIdx.x;
    int t = idx & 15, bc = idx >> 4;
    int c = bc & 255;
    int yo = t >> 2, xo = t & 3;
    float acc = rb[c];
    const float* w = rw + c * 16;
    const float* base = red1 + (size_t)bc * 256;
#pragma unroll
    for (int dy = 0; dy < 4; dy++)
#pragma unroll
        for (int dx = 0; dx < 4; dx++)
            acc += base[(yo * 4 + dy) * 16 + xo * 4 + dx] * w[dy * 4 + dx];
    red2[idx] = acc;
}

__global__ void k_dw3(const float* __restrict__ in, const float* __restrict__ w9,
                      const float* __restrict__ bb, float* __restrict__ outp) {
    int idx = blockIdx.x * 256 + threadIdx.x;
    int t = idx & 15, bc = idx >> 4, c = bc & 255;
    int y = t >> 2, x = t & 3;
    float acc = bb[c];
    const float* w = w9 + c * 9;
    const float* base = in + (size_t)bc * 16;
#pragma unroll
    for (int dy = -1; dy <= 1; dy++)
#pragma unroll
        for (int dx = -1; dx <= 1; dx++) {
            int yy = y + dy, xx = x + dx;
            if (yy >= 0 && yy < 4 && xx >= 0 && xx < 4)
                acc += base[yy * 4 + xx] * w[(dy + 1) * 3 + (dx + 1)];
        }
    outp[idx] = acc;
}

__global__ void k_conv1x1_ln(const float* __restrict__ dwr, const float* __restrict__ cw,
                             const float* __restrict__ cb, const float* __restrict__ naw,
                             const float* __restrict__ nab, float* __restrict__ xr) {
    int b = blockIdx.x >> 4, m = blockIdx.x & 15;
    int tid = threadIdx.x;
    __shared__ float in[256];
    for (int c = tid; c < 256; c += 128) in[c] = dwr[((size_t)b * Cn + c) * 16 + m];
    __syncthreads();
    float acc = cb[tid];
    const float* w = cw + tid * 256;
    for (int c = 0; c < 256; c++) acc += in[c] * w[c];
    float2 r = block_sum2<128>(acc, acc * acc);
    float mm = r.x * (1.f / 128.f), var = r.y * (1.f / 128.f) - mm * mm;
    float inv = rsqrtf(fmaxf(var, 0.f) + 1e-5f);
    float z = (acc - mm) * inv * naw[tid] + nab[tid];
    xr[(size_t)blockIdx.x * 128 + tid] = gelu_f(z);
}

__global__ void k_kv(const float* __restrict__ xr, const float* __restrict__ kw,
                     const float* __restrict__ vw, float* __restrict__ kbuf, float* __restrict__ v0) {
    int bm = blockIdx.x;
    int tid = threadIdx.x;
    __shared__ float in[128];
    if (tid < 128) in[tid] = xr[(size_t)bm * 128 + tid];
    __syncthreads();
    float acc = 0.f;
    for (int i = 0; i < 128; i++) acc += in[i] * vw[i * 256 + tid];
    v0[(size_t)bm * 256 + tid] = acc;
    if (tid < 128) {
        float ak = 0.f;
        for (int i = 0; i < 128; i++) ak += in[i] * kw[i * 128 + tid];
        kbuf[(size_t)bm * 128 + tid] = ak;
    }
}

__global__ void k_cpe(const float* __restrict__ v0, const float* __restrict__ cw,
                      const float* __restrict__ cb, float* __restrict__ v) {
    int idx = blockIdx.x * 256 + threadIdx.x;
    int c = idx & 255, bm = idx >> 8;
    int b = bm >> 4, m = bm & 15;
    int y = m >> 2, x = m & 3;
    float acc = v0[idx] + cb[c];
#pragma unroll
    for (int dy = -1; dy <= 1; dy++)
#pragma unroll
        for (int dx = -1; dx <= 1; dx++) {
            int yy = y + dy, xx = x + dx;
            if (yy >= 0 && yy < 4 && xx >= 0 && xx < 4)
                acc += v0[((size_t)b * 16 + yy * 4 + xx) * 256 + c] * cw[c * 9 + (dy + 1) * 3 + (dx + 1)];
        }
    v[idx] = acc;
}

// ---- K10: one task (row,head) per thread; 32 rows/block; K/V in LDS;
// q read and o written DIRECTLY (8 lanes x 64B = contiguous 512B per row).
// No qs/os staging, no it-loop => ~64 live floats/thread, no spill.
__global__ void __launch_bounds__(256, 2)
k_attn(const bf16* __restrict__ q, const float* __restrict__ kbuf,
       const float* __restrict__ v, bf16* o) {
    __shared__ float ks2[8 * 260];
    __shared__ float vs2[8 * 516];
    int tid = threadIdx.x;
    int b = blockIdx.x >> 7, chunk = blockIdx.x & 127;
    int n = chunk * 32 + (tid >> 3);
    int h = tid & 7;
    const float* kbp = kbuf + (size_t)b * 2048;
    for (int i = tid; i < 2048; i += 256) {
        int m = i >> 7, rem = i & 127, hh = rem >> 4, d = rem & 15;
        ks2[hh * 260 + m * 16 + d] = kbp[i];
    }
    const float* vbp = v + (size_t)b * 4096;
    for (int i = tid; i < 4096; i += 256) {
        int m = i >> 8, rem = i & 255, hh = rem >> 5, e = rem & 31;
        vs2[hh * 516 + m * 32 + e] = vbp[i];
    }
    __syncthreads();
    const bf16* qp = q + ((size_t)b * 4096 + n) * 128 + h * 16;
    short qsv[16];
    *(uint4*)(qsv) = *(const uint4*)qp;
    *(uint4*)(qsv + 8) = *(const uint4*)(qp + 8);
    float qr[16];
#pragma unroll
    for (int d = 0; d < 16; d++) qr[d] = b2f(*(const bf16*)&qsv[d]);
    const float* kh = ks2 + h * 260;
    float sc[16];
    float mx = -1e30f;
#pragma unroll
    for (int m = 0; m < 16; m++) {
        float s = 0.f;
#pragma unroll
        for (int d = 0; d < 16; d++) s += qr[d] * kh[m * 16 + d];
        s *= 0.25f;
        sc[m] = s;
        mx = fmaxf(mx, s);
    }
    float den = 0.f;
#pragma unroll
    for (int m = 0; m < 16; m++) { sc[m] = expf(sc[m] - mx); den += sc[m]; }
    float rden = 1.f / den;
    const float* vh = vs2 + h * 516;
    float ov[32];
#pragma unroll
    for (int e = 0; e < 32; e++) ov[e] = 0.f;
#pragma unroll
    for (int m = 0; m < 16; m++) {
        float p = sc[m] * rden;
#pragma unroll
        for (int e = 0; e < 32; e++) ov[e] += p * vh[m * 32 + e];
    }
    bf16* op = o + ((size_t)b * 4096 + n) * 256 + h * 32;
#pragma unroll
    for (int g = 0; g < 4; g++) {
        uint4 u;
        short* ts = (short*)&u;
#pragma unroll
        for (int j = 0; j < 8; j++) {
            bf16 hv = f2b(ov[g * 8 + j]);
            ts[j] = *(short*)&hv;
        }
        *(uint4*)(op + g * 8) = u;
    }
}

__global__ void k_ln_res(const bf16* __restrict__ po, const float* __restrict__ x,
                         const float* __restrict__ xh, const float* __restrict__ xw,
                         const float* __restrict__ n2w, const float* __restrict__ n2b,
                         bf16* __restrict__ tn2) {
    __shared__ float t1s[16][256];
    int tid = threadIdx.x, c = tid;
    size_t row0 = (size_t)blockIdx.x * 16;
    int b = (int)(row0 >> 12);
    int n0 = (int)(row0 & 4095);
    int hh = n0 >> 6, w0 = n0 & 63;
    float hg = xh[((size_t)b * 256 + c) * 64 + hh];
    const float* xp = x + (((size_t)b * 256 + c) * 64 + hh) * 64 + w0;
    const float* wp = xw + ((size_t)b * 256 + c) * 64 + w0;
    for (int r = 0; r < 16; r++)
        t1s[r][c] = b2f(po[(row0 + r) * 256 + c]) + xp[r] * hg * wp[r];
    __syncthreads();
    int wv = tid >> 6, lane = tid & 63;
    float nw[4], nb[4];
#pragma unroll
    for (int k2 = 0; k2 < 4; k2++) { nw[k2] = n2w[lane + k2 * 64]; nb[k2] = n2b[lane + k2 * 64]; }
    for (int rr = 0; rr < 4; rr++) {
        int r = wv * 4 + rr;
        float s = 0.f, s2 = 0.f;
#pragma unroll
        for (int k2 = 0; k2 < 4; k2++) { float v = t1s[r][lane + k2 * 64]; s += v; s2 += v * v; }
#pragma unroll
        for (int off2 = 32; off2; off2 >>= 1) { s += __shfl_down(s, off2); s2 += __shfl_down(s2, off2); }
        s = __shfl(s, 0); s2 = __shfl(s2, 0);
        float m = s * (1.f / 256.f), var = s2 * (1.f / 256.f) - m * m;
        float inv = rsqrtf(fmaxf(var, 0.f) + 1e-6f);
#pragma unroll
        for (int k2 = 0; k2 < 4; k2++) {
            int cc = lane + k2 * 64;
            float v = t1s[r][cc];
            tn2[(row0 + r) * 256 + cc] = f2b((v - m) * inv * nw[k2] + nb[k2]);
        }
    }
}

__global__ void k_ln512(bf16* __restrict__ x2, const float* __restrict__ gnw,
                        const float* __restrict__ gnb) {
    __shared__ float s[16][512];
    int tid = threadIdx.x;
    size_t row0 = (size_t)blockIdx.x * 16;
    for (int i = tid; i < 16 * 512; i += 256) s[i >> 9][i & 511] = b2f(x2[row0 * 512 + i]);
    __syncthreads();
    int wv = tid >> 6, lane = tid & 63;
    float nw[8], nb[8];
#pragma unroll
    for (int k2 = 0; k2 < 8; k2++) { nw[k2] = gnw[lane + k2 * 64]; nb[k2] = gnb[lane + k2 * 64]; }
    for (int rr = 0; rr < 4; rr++) {
        int r = wv * 4 + rr;
        float a = 0.f, a2 = 0.f;
#pragma unroll
        for (int k2 = 0; k2 < 8; k2++) { float v = s[r][lane + k2 * 64]; a += v; a2 += v * v; }
#pragma unroll
        for (int off2 = 32; off2; off2 >>= 1) { a += __shfl_down(a, off2); a2 += __shfl_down(a2, off2); }
        a = __shfl(a, 0); a2 = __shfl(a2, 0);
        float m = a * (1.f / 512.f), var = a2 * (1.f / 512.f) - m * m;
        float inv = rsqrtf(fmaxf(var, 0.f) + 1e-5f);
#pragma unroll
        for (int k2 = 0; k2 < 8; k2++) {
            int e = lane + k2 * 64;
            float v = (s[r][e] - m) * inv * nw[k2] + nb[k2];
            x2[(row0 + r) * 512 + e] = f2b(v);
        }
    }
}

__global__ void k_gatec(const bf16* __restrict__ x2n, const float* __restrict__ gw,
                        const float* __restrict__ gb, bf16* __restrict__ x1io) {
    size_t idx = (size_t)blockIdx.x * 256 + threadIdx.x;
    int c = (int)(idx & 511);
    size_t bn = idx >> 9;
    int n = (int)(bn & 4095);
    size_t b = bn >> 12;
    int y = n >> 6, x = n & 63;
    float acc = gb[c];
    const float* w = gw + c * 9;
#pragma unroll
    for (int dy = -1; dy <= 1; dy++)
#pragma unroll
        for (int dx = -1; dx <= 1; dx++) {
            int yy = y + dy, xx = x + dx;
            if (yy >= 0 && yy < 64 && xx >= 0 && xx < 64)
                acc += b2f(x2n[(b * Nn + yy * 64 + xx) * 512 + c]) * w[(dy + 1) * 3 + (dx + 1)];
        }
    float g = b2f(x1io[idx]) * acc;
    x1io[idx] = f2b(g);
}

extern "C" void kernel_launch(void* const* d_in, const int* in_sizes, int n_in,
                              void* d_out, int out_size, void* d_ws, size_t ws_size,
                              hipStream_t stream) {
    const float* x = (const float*)d_in[0];
    const float* sda_conv_w = (const float*)d_in[1];
    const float* sda_gn_w = (const float*)d_in[2];
    const float* sda_gn_b = (const float*)d_in[3];
    const float* norm1_w = (const float*)d_in[4];
    const float* norm1_b = (const float*)d_in[5];
    const float* red_w = (const float*)d_in[6];
    const float* red_b = (const float*)d_in[7];
    const float* dw_w = (const float*)d_in[8];
    const float* dw_b = (const float*)d_in[9];
    const float* conv_w = (const float*)d_in[10];
    const float* conv_b = (const float*)d_in[11];
    const float* na_w = (const float*)d_in[12];
    const float* na_b = (const float*)d_in[13];
    const float* q_w = (const float*)d_in[14];
    const float* k_w = (const float*)d_in[15];
    const float* v_w = (const float*)d_in[16];
    const float* cpe_w = (const float*)d_in[17];
    const float* cpe_b = (const float*)d_in[18];
    const float* proj_w = (const float*)d_in[19];
    const float* proj_b = (const float*)d_in[20];
    const float* norm2_w = (const float*)d_in[21];
    const float* norm2_b = (const float*)d_in[22];
    const float* fc1_w = (const float*)d_in[23];
    const float* fc1_b = (const float*)d_in[24];
    const float* gnorm_w = (const float*)d_in[25];
    const float* gnorm_b = (const float*)d_in[26];
    const float* gconv_w = (const float*)d_in[27];
    const float* gconv_b = (const float*)d_in[28];
    const float* fc2_w = (const float*)d_in[29];
    const float* fc2_b = (const float*)d_in[30];
    float* outp = (float*)d_out;

    char* ws = (char*)d_ws;
    size_t off = 0;
    auto alloc = [&](size_t bytes) -> char* {
        char* p = ws + off;
        off += (bytes + 255) & ~(size_t)255;
        return p;
    };
    bf16* po = (bf16*)alloc((size_t)Mtot * Cn * 2);
    char* arena2 = alloc((size_t)Mtot * HALFn * 2);
    char* arena3 = alloc((size_t)Mtot * HALFn * 2);
    float* xmH = (float*)alloc((size_t)Bn * Cn * 64 * 4);
    float* xmW = (float*)alloc((size_t)Bn * Cn * 64 * 4);
    float* xh = (float*)alloc((size_t)Bn * Cn * 64 * 4);
    float* xw = (float*)alloc((size_t)Bn * Cn * 64 * 4);
    float* red2 = (float*)alloc((size_t)Bn * Cn * 16 * 4);
    float* dwr = (float*)alloc((size_t)Bn * Cn * 16 * 4);
    float* xr = (float*)alloc((size_t)Bn * 16 * 128 * 4);
    float* kb = (float*)alloc((size_t)Bn * 16 * 128 * 4);
    float* v0 = (float*)alloc((size_t)Bn * 16 * 256 * 4);
    float* vb = (float*)alloc((size_t)Bn * 16 * 256 * 4);
    bf16* qwT = (bf16*)alloc((size_t)128 * 256 * 2);
    bf16* pwT = (bf16*)alloc((size_t)256 * 256 * 2);
    bf16* f1T = (bf16*)alloc((size_t)1024 * 256 * 2);
    bf16* f2T = (bf16*)alloc((size_t)256 * 512 * 2);

    bf16* tn = (bf16*)d_out;
    bf16* qb = (bf16*)arena2;
    bf16* x1 = (bf16*)arena2;
    float* red1 = (float*)arena3;
    bf16* x2b = (bf16*)arena3;

    k_cvtw<<<(256 / 32) * (128 / 32), 256, 0, stream>>>(q_w, qwT, 256, 128);
    k_cvtw<<<(256 / 32) * (256 / 32), 256, 0, stream>>>(proj_w, pwT, 256, 256);
    k_cvtw<<<(256 / 32) * (1024 / 32), 256, 0, stream>>>(fc1_w, f1T, 256, 1024);
    k_cvtw<<<(512 / 32) * (256 / 32), 256, 0, stream>>>(fc2_w, f2T, 512, 256);

    k_pool<<<Bn * Cn, 256, 0, stream>>>(x, xmH, xmW);
    k_sda<<<Bn * 16, 256, 0, stream>>>(xmH, xmW, sda_conv_w, sda_gn_w, sda_gn_b, xh, xw);
    k_gate_norm1<<<Bn * 64, 256, 0, stream>>>(x, xh, xw, norm1_w, norm1_b, tn);
    k_red1<<<Bn * 16 * 4, 256, 0, stream>>>(tn, red_w, red_b, red1);
    k_red2<<<256, 256, 0, stream>>>(red1, red_w, red_b, red2);
    k_dw3<<<256, 256, 0, stream>>>(red2, dw_w, dw_b, dwr);
    k_conv1x1_ln<<<Bn * 16, 128, 0, stream>>>(dwr, conv_w, conv_b, na_w, na_b, xr);
    k_kv<<<Bn * 16, 256, 0, stream>>>(xr, k_w, v_w, kb, v0);
    k_cpe<<<256, 256, 0, stream>>>(v0, cpe_w, cpe_b, vb);
    gemm_q<<<(Mtot / 64) * 2, 256, 0, stream>>>(tn, qwT, qb);
    k_attn<<<Bn * 128, 256, 0, stream>>>(qb, kb, vb, tn);
    gemm_proj<<<(Mtot / 64) * 4, 256, 0, stream>>>(tn, pwT, proj_b, po);
    k_ln_res<<<Mtot / 16, 256, 0, stream>>>(po, x, xh, xw, norm2_w, norm2_b, tn);
    gemm_fc1<<<(Mtot / 64) * 16, 256, 0, stream>>>(tn, f1T, fc1_b, x1, x2b);
    k_ln512<<<Mtot / 16, 256, 0, stream>>>(x2b, gnorm_w, gnorm_b);
    k_gatec<<<(Mtot * HALFn) / 256, 256, 0, stream>>>(x2b, gconv_w, gconv_b, x1);
    gemm_fc2<<<(Mtot / 64) * 4, 256, 0, stream>>>(x1, f2T, fc2_b, po, x, xh, xw, outp);
}